// Round 1
// baseline (735.836 us; speedup 1.0000x reference)
//
#include <hip/hip_runtime.h>
#include <math.h>

#define N_NODES 100000
#define N_EDGES 1000000
#define HDIM 64
#define NGRAPH 256
#define NCLASS 8

#define SCAN_CH 1024
#define SCAN_NB ((N_NODES + SCAN_CH - 1) / SCAN_CH)   // 98

// ---------------- degree count ----------------
__global__ void k_count(const int* __restrict__ row, int* __restrict__ counts) {
    int e = blockIdx.x * blockDim.x + threadIdx.x;
    if (e < N_EDGES) atomicAdd(&counts[row[e]], 1);
}

// ---------------- 2-level exclusive scan ----------------
__global__ void k_scan_part(const int* __restrict__ counts, int* __restrict__ partial) {
    __shared__ int sd[256];
    int b = blockIdx.x, t = threadIdx.x;
    int base = b * SCAN_CH + t * 4;
    int s = 0;
#pragma unroll
    for (int j = 0; j < 4; ++j) {
        int idx = base + j;
        if (idx < N_NODES) s += counts[idx];
    }
    sd[t] = s; __syncthreads();
    for (int off = 128; off >= 1; off >>= 1) {
        if (t < off) sd[t] += sd[t + off];
        __syncthreads();
    }
    if (t == 0) partial[b] = sd[0];
}

__global__ void k_scan_top(const int* __restrict__ partial, int* __restrict__ coff) {
    if (threadIdx.x == 0 && blockIdx.x == 0) {
        int run = 0;
        for (int b = 0; b < SCAN_NB; ++b) { coff[b] = run; run += partial[b]; }
    }
}

__global__ void k_scan_final(const int* __restrict__ counts, const int* __restrict__ coff,
                             int* __restrict__ start, float* __restrict__ dinv) {
    __shared__ int sd[256];
    int b = blockIdx.x, t = threadIdx.x;
    int base = b * SCAN_CH + t * 4;
    int c[4]; int s = 0;
#pragma unroll
    for (int j = 0; j < 4; ++j) {
        int idx = base + j;
        c[j] = (idx < N_NODES) ? counts[idx] : 0;
        s += c[j];
    }
    sd[t] = s; __syncthreads();
    for (int off = 1; off < 256; off <<= 1) {
        int v = (t >= off) ? sd[t - off] : 0;
        __syncthreads();
        sd[t] += v;
        __syncthreads();
    }
    int run = sd[t] - s + coff[b];
#pragma unroll
    for (int j = 0; j < 4; ++j) {
        int idx = base + j;
        if (idx < N_NODES) {
            start[idx] = run;
            run += c[j];
            dinv[idx] = rsqrtf((float)(c[j] + 1));
        }
    }
}

// ---------------- CSR scatter ----------------
__global__ void k_scatter(const int* __restrict__ row, const int* __restrict__ col,
                          const float* __restrict__ dinv, const int* __restrict__ start,
                          int* __restrict__ cursor, int2* __restrict__ csr) {
    int e = blockIdx.x * blockDim.x + threadIdx.x;
    if (e >= N_EDGES) return;
    int r = row[e], c = col[e];
    float w = 0.5f * dinv[r] * dinv[c];   // (1-alpha) * norm folded in
    int p = start[r] + atomicAdd(&cursor[r], 1);
    csr[p] = make_int2(c, __float_as_int(w));
}

// ---------------- h0 = x @ W_sgc + b_sgc ----------------
__global__ void k_h0(const float* __restrict__ x, const float* __restrict__ W,
                     const float* __restrict__ bias, float* __restrict__ h0) {
    __shared__ float Ws[64 * 64];
    int t = threadIdx.x;
    for (int i = t; i < 4096; i += 256) Ws[i] = W[i];
    __syncthreads();
    int wave = t >> 6, lane = t & 63;
    float bl = bias[lane];
    for (int rr = wave; rr < 64; rr += 4) {
        int r = blockIdx.x * 64 + rr;
        if (r >= N_NODES) break;
        float xv = x[r * 64 + lane];
        float acc = bl;
#pragma unroll
        for (int k = 0; k < 64; ++k)
            acc += __shfl(xv, k, 64) * Ws[k * 64 + lane];
        h0[r * 64 + lane] = acc;
    }
}

// ---------------- propagation hop (gather formulation) ----------------
__device__ __forceinline__ float hop_acc(int node, int lane,
        const float* __restrict__ h_in, const float* __restrict__ h0,
        const float* __restrict__ dinv, const int* __restrict__ start,
        const int* __restrict__ counts, const int2* __restrict__ csr) {
    float di = dinv[node];
    float acc = 0.5f * di * di * h_in[node * 64 + lane] + 0.5f * h0[node * 64 + lane];
    int s = start[node], cnt = counts[node];
    for (int base = 0; base < cnt; base += 64) {
        int m = cnt - base; if (m > 64) m = 64;
        int cc = 0; float ww = 0.f;
        if (lane < m) {
            int2 cw = csr[s + base + lane];
            cc = cw.x; ww = __int_as_float(cw.y);
        }
        for (int j = 0; j < m; ++j) {
            int c = __shfl(cc, j, 64);
            float w = __shfl(ww, j, 64);
            acc += w * h_in[c * 64 + lane];
        }
    }
    return acc;
}

__global__ void k_hop(const float* __restrict__ h_in, const float* __restrict__ h0,
                      const float* __restrict__ dinv, const int* __restrict__ start,
                      const int* __restrict__ counts, const int2* __restrict__ csr,
                      float* __restrict__ h_out) {
    int node = blockIdx.x * 4 + (threadIdx.x >> 6);
    int lane = threadIdx.x & 63;
    if (node >= N_NODES) return;
    h_out[node * 64 + lane] = hop_acc(node, lane, h_in, h0, dinv, start, counts, csr);
}

// final hop fused with relu + attention gate dot product
__global__ void k_hop_final(const float* __restrict__ h_in, const float* __restrict__ h0,
                            const float* __restrict__ dinv, const int* __restrict__ start,
                            const int* __restrict__ counts, const int2* __restrict__ csr,
                            const float* __restrict__ w_att, const float* __restrict__ b_att,
                            float* __restrict__ h_out, float* __restrict__ v_raw) {
    int node = blockIdx.x * 4 + (threadIdx.x >> 6);
    int lane = threadIdx.x & 63;
    if (node >= N_NODES) return;
    float acc = hop_acc(node, lane, h_in, h0, dinv, start, counts, csr);
    float hv = fmaxf(acc, 0.f);
    h_out[node * 64 + lane] = hv;
    float p = hv * w_att[lane];
#pragma unroll
    for (int off = 32; off >= 1; off >>= 1) p += __shfl_xor(p, off, 64);
    if (lane == 0) {
        v_raw[node] = 1.f / (1.f + expf(-(p + b_att[0])));
    }
}

// ---------------- graph ranges (batch is sorted) ----------------
__global__ void k_bounds(const int* __restrict__ batch, int* __restrict__ gstart,
                         int* __restrict__ gend) {
    int n = blockIdx.x * blockDim.x + threadIdx.x;
    if (n >= N_NODES) return;
    int b = batch[n];
    atomicMin(&gstart[b], n);
    atomicMax(&gend[b], n + 1);
}

// ---------------- readout + MLP head, one block per graph ----------------
__global__ void k_readout_mlp(const float* __restrict__ h, const float* __restrict__ v_raw,
        const int* __restrict__ gstart, const int* __restrict__ gend,
        const float* __restrict__ W1, const float* __restrict__ b1,
        const float* __restrict__ W2, const float* __restrict__ b2,
        const float* __restrict__ W3, const float* __restrict__ b3,
        float* __restrict__ out) {
    int g = blockIdx.x, t = threadIdx.x;
    int s = gstart[g], e = gend[g];
    __shared__ float red[256];

    // segment max of v
    float m = -3.402823466e38f;
    for (int n = s + t; n < e; n += 256) m = fmaxf(m, v_raw[n]);
    red[t] = m; __syncthreads();
    for (int off = 128; off >= 1; off >>= 1) {
        if (t < off) red[t] = fmaxf(red[t], red[t + off]);
        __syncthreads();
    }
    float vmax = red[0]; __syncthreads();

    // segment sum of exp(v - vmax)
    float ss = 0.f;
    for (int n = s + t; n < e; n += 256) ss += expf(v_raw[n] - vmax);
    red[t] = ss; __syncthreads();
    for (int off = 128; off >= 1; off >>= 1) {
        if (t < off) red[t] += red[t + off];
        __syncthreads();
    }
    float inv = 1.f / (red[0] + 1e-16f);
    __syncthreads();

    // gmp (segment max of h) and gsp (sum of v*h): 4 waves split nodes, lane=feature
    int wv = t >> 6, lane = t & 63;
    float gm = -3.402823466e38f, gs = 0.f;
    for (int n = s + wv; n < e; n += 4) {
        float hv = h[n * 64 + lane];
        float vn = expf(v_raw[n] - vmax) * inv;
        gm = fmaxf(gm, hv);
        gs += vn * hv;
    }
    __shared__ float pm[4][64], ps[4][64];
    pm[wv][lane] = gm; ps[wv][lane] = gs;
    __syncthreads();

    __shared__ float z[128];
    if (t < 64) {
        z[t] = fmaxf(fmaxf(pm[0][t], pm[1][t]), fmaxf(pm[2][t], pm[3][t]));
        z[64 + t] = ps[0][t] + ps[1][t] + ps[2][t] + ps[3][t];
    }
    __syncthreads();

    // MLP head
    __shared__ float z1[64];
    if (t < 64) {
        float a = b1[t];
#pragma unroll 8
        for (int k = 0; k < 128; ++k) a += z[k] * W1[k * 64 + t];
        z1[t] = fmaxf(a, 0.f);
    }
    __syncthreads();
    __shared__ float z2[32];
    if (t < 32) {
        float a = b2[t];
#pragma unroll 8
        for (int k = 0; k < 64; ++k) a += z1[k] * W2[k * 32 + t];
        z2[t] = fmaxf(a, 0.f);
    }
    __syncthreads();
    __shared__ float z3[8];
    if (t < 8) {
        float a = b3[t];
#pragma unroll
        for (int k = 0; k < 32; ++k) a += z2[k] * W3[k * 8 + t];
        z3[t] = a;
    }
    __syncthreads();
    if (t == 0) {
        float mx = z3[0];
#pragma unroll
        for (int j = 1; j < 8; ++j) mx = fmaxf(mx, z3[j]);
        float se = 0.f;
#pragma unroll
        for (int j = 0; j < 8; ++j) se += expf(z3[j] - mx);
        float lse = mx + logf(se);
#pragma unroll
        for (int j = 0; j < 8; ++j) out[g * 8 + j] = z3[j] - lse;
    }
}

extern "C" void kernel_launch(void* const* d_in, const int* in_sizes, int n_in,
                              void* d_out, int out_size, void* d_ws, size_t ws_size,
                              hipStream_t stream) {
    const float* x     = (const float*)d_in[0];
    const int*   edge  = (const int*)d_in[1];
    const int*   row   = edge;
    const int*   col   = edge + N_EDGES;
    const int*   batch = (const int*)d_in[2];
    const float* W_sgc = (const float*)d_in[3];
    const float* b_sgc = (const float*)d_in[4];
    const float* w_att = (const float*)d_in[5];
    const float* b_att = (const float*)d_in[6];
    const float* W1    = (const float*)d_in[7];
    const float* b1    = (const float*)d_in[8];
    const float* W2    = (const float*)d_in[9];
    const float* b2    = (const float*)d_in[10];
    const float* W3    = (const float*)d_in[11];
    const float* b3    = (const float*)d_in[12];
    float* out = (float*)d_out;

    char* p = (char*)d_ws;
    auto alloc = [&](size_t bytes) {
        char* r = p;
        p += (bytes + 255) & ~(size_t)255;
        return r;
    };
    int*   counts  = (int*)alloc((size_t)N_NODES * 4);
    int*   cursor  = (int*)alloc((size_t)N_NODES * 4);
    int*   gend    = (int*)alloc((size_t)NGRAPH * 4);
    int*   gstart  = (int*)alloc((size_t)NGRAPH * 4);
    int*   start   = (int*)alloc((size_t)N_NODES * 4);
    int*   partial = (int*)alloc((size_t)SCAN_NB * 4);
    int*   coff    = (int*)alloc((size_t)SCAN_NB * 4);
    float* dinv    = (float*)alloc((size_t)N_NODES * 4);
    float* vraw    = (float*)alloc((size_t)N_NODES * 4);
    float* h0      = (float*)alloc((size_t)N_NODES * 64 * 4);
    float* hA      = (float*)alloc((size_t)N_NODES * 64 * 4);
    float* hB      = (float*)alloc((size_t)N_NODES * 64 * 4);
    int2*  csr     = (int2*)alloc((size_t)N_EDGES * 8);

    // zero counts+cursor+gend (contiguous), set gstart to large sentinel
    hipMemsetAsync(counts, 0, (size_t)((char*)gstart - (char*)counts), stream);
    hipMemsetAsync(gstart, 0x7f, (size_t)NGRAPH * 4, stream);

    k_count<<<(N_EDGES + 255) / 256, 256, 0, stream>>>(row, counts);
    k_scan_part<<<SCAN_NB, 256, 0, stream>>>(counts, partial);
    k_scan_top<<<1, 64, 0, stream>>>(partial, coff);
    k_scan_final<<<SCAN_NB, 256, 0, stream>>>(counts, coff, start, dinv);
    k_scatter<<<(N_EDGES + 255) / 256, 256, 0, stream>>>(row, col, dinv, start, cursor, csr);
    k_h0<<<(N_NODES + 63) / 64, 256, 0, stream>>>(x, W_sgc, b_sgc, h0);
    k_hop<<<(N_NODES + 3) / 4, 256, 0, stream>>>(h0, h0, dinv, start, counts, csr, hA);
    k_hop<<<(N_NODES + 3) / 4, 256, 0, stream>>>(hA, h0, dinv, start, counts, csr, hB);
    k_hop_final<<<(N_NODES + 3) / 4, 256, 0, stream>>>(hB, h0, dinv, start, counts, csr,
                                                       w_att, b_att, hA, vraw);
    k_bounds<<<(N_NODES + 255) / 256, 256, 0, stream>>>(batch, gstart, gend);
    k_readout_mlp<<<NGRAPH, 256, 0, stream>>>(hA, vraw, gstart, gend,
                                              W1, b1, W2, b2, W3, b3, out);
}

// Round 3
// 504.784 us; speedup vs baseline: 1.4577x; 1.4577x over previous
//
#include <hip/hip_runtime.h>
#include <math.h>

#define N_NODES 100000
#define N_EDGES 1000000
#define HDIM 64
#define NGRAPH 256
#define NCLASS 8

#define SCAN_CH 1024
#define SCAN_NB ((N_NODES + SCAN_CH - 1) / SCAN_CH)   // 98

// ---------------- degree count ----------------
__global__ void k_count(const int* __restrict__ row, int* __restrict__ counts) {
    int e = blockIdx.x * blockDim.x + threadIdx.x;
    if (e < N_EDGES) atomicAdd(&counts[row[e]], 1);
}

// ---------------- 2-level exclusive scan ----------------
__global__ void k_scan_part(const int* __restrict__ counts, int* __restrict__ partial) {
    __shared__ int sd[256];
    int b = blockIdx.x, t = threadIdx.x;
    int base = b * SCAN_CH + t * 4;
    int s = 0;
#pragma unroll
    for (int j = 0; j < 4; ++j) {
        int idx = base + j;
        if (idx < N_NODES) s += counts[idx];
    }
    sd[t] = s; __syncthreads();
    for (int off = 128; off >= 1; off >>= 1) {
        if (t < off) sd[t] += sd[t + off];
        __syncthreads();
    }
    if (t == 0) partial[b] = sd[0];
}

__global__ void k_scan_top(const int* __restrict__ partial, int* __restrict__ coff) {
    if (threadIdx.x == 0 && blockIdx.x == 0) {
        int run = 0;
        for (int b = 0; b < SCAN_NB; ++b) { coff[b] = run; run += partial[b]; }
    }
}

__global__ void k_scan_final(const int* __restrict__ counts, const int* __restrict__ coff,
                             int* __restrict__ start, float* __restrict__ dinv) {
    __shared__ int sd[256];
    int b = blockIdx.x, t = threadIdx.x;
    int base = b * SCAN_CH + t * 4;
    int c[4]; int s = 0;
#pragma unroll
    for (int j = 0; j < 4; ++j) {
        int idx = base + j;
        c[j] = (idx < N_NODES) ? counts[idx] : 0;
        s += c[j];
    }
    sd[t] = s; __syncthreads();
    for (int off = 1; off < 256; off <<= 1) {
        int v = (t >= off) ? sd[t - off] : 0;
        __syncthreads();
        sd[t] += v;
        __syncthreads();
    }
    int run = sd[t] - s + coff[b];
#pragma unroll
    for (int j = 0; j < 4; ++j) {
        int idx = base + j;
        if (idx < N_NODES) {
            start[idx] = run;
            run += c[j];
            dinv[idx] = rsqrtf((float)(c[j] + 1));
        }
    }
}

// ---------------- CSR scatter ----------------
__global__ void k_scatter(const int* __restrict__ row, const int* __restrict__ col,
                          const float* __restrict__ dinv, const int* __restrict__ start,
                          int* __restrict__ cursor, int2* __restrict__ csr) {
    int e = blockIdx.x * blockDim.x + threadIdx.x;
    if (e >= N_EDGES) return;
    int r = row[e], c = col[e];
    float w = 0.5f * dinv[r] * dinv[c];   // (1-alpha) * norm folded in
    int p = start[r] + atomicAdd(&cursor[r], 1);
    csr[p] = make_int2(c, __float_as_int(w));
}

// ---------------- h0 = x @ W_sgc + b_sgc ----------------
__global__ void k_h0(const float* __restrict__ x, const float* __restrict__ W,
                     const float* __restrict__ bias, float* __restrict__ h0) {
    __shared__ float Ws[64 * 64];
    int t = threadIdx.x;
    for (int i = t; i < 4096; i += 256) Ws[i] = W[i];
    __syncthreads();
    int wave = t >> 6, lane = t & 63;
    float bl = bias[lane];
    for (int rr = wave; rr < 64; rr += 4) {
        int r = blockIdx.x * 64 + rr;
        if (r >= N_NODES) break;
        float xv = x[r * 64 + lane];
        float acc = bl;
#pragma unroll
        for (int k = 0; k < 64; ++k)
            acc += __shfl(xv, k, 64) * Ws[k * 64 + lane];
        h0[r * 64 + lane] = acc;
    }
}

// ---------------- propagation hop (gather, 4-wide MLP) ----------------
__device__ __forceinline__ float hop_acc(int node, int lane,
        const float* __restrict__ h_in, const float* __restrict__ h0,
        const float* __restrict__ dinv, const int* __restrict__ start,
        const int* __restrict__ counts, const int2* __restrict__ csr) {
    float di = dinv[node];
    float acc = 0.5f * di * di * h_in[node * 64 + lane] + 0.5f * h0[node * 64 + lane];
    int s = start[node], cnt = counts[node];
    int j = 0;
    for (; j + 4 <= cnt; j += 4) {
        // all lanes load the same edge record -> broadcast, L1-hit
        int2 e0 = csr[s + j];
        int2 e1 = csr[s + j + 1];
        int2 e2 = csr[s + j + 2];
        int2 e3 = csr[s + j + 3];
        float v0 = h_in[e0.x * 64 + lane];
        float v1 = h_in[e1.x * 64 + lane];
        float v2 = h_in[e2.x * 64 + lane];
        float v3 = h_in[e3.x * 64 + lane];
        acc += __int_as_float(e0.y) * v0;
        acc += __int_as_float(e1.y) * v1;
        acc += __int_as_float(e2.y) * v2;
        acc += __int_as_float(e3.y) * v3;
    }
    for (; j < cnt; ++j) {
        int2 e0 = csr[s + j];
        acc += __int_as_float(e0.y) * h_in[e0.x * 64 + lane];
    }
    return acc;
}

__global__ void k_hop(const float* __restrict__ h_in, const float* __restrict__ h0,
                      const float* __restrict__ dinv, const int* __restrict__ start,
                      const int* __restrict__ counts, const int2* __restrict__ csr,
                      float* __restrict__ h_out) {
    int node = blockIdx.x * 4 + (threadIdx.x >> 6);
    int lane = threadIdx.x & 63;
    if (node >= N_NODES) return;
    h_out[node * 64 + lane] = hop_acc(node, lane, h_in, h0, dinv, start, counts, csr);
}

// final hop fused with relu + attention gate dot product
__global__ void k_hop_final(const float* __restrict__ h_in, const float* __restrict__ h0,
                            const float* __restrict__ dinv, const int* __restrict__ start,
                            const int* __restrict__ counts, const int2* __restrict__ csr,
                            const float* __restrict__ w_att, const float* __restrict__ b_att,
                            float* __restrict__ h_out, float* __restrict__ v_raw) {
    int node = blockIdx.x * 4 + (threadIdx.x >> 6);
    int lane = threadIdx.x & 63;
    if (node >= N_NODES) return;
    float acc = hop_acc(node, lane, h_in, h0, dinv, start, counts, csr);
    float hv = fmaxf(acc, 0.f);
    h_out[node * 64 + lane] = hv;
    float p = hv * w_att[lane];
#pragma unroll
    for (int off = 32; off >= 1; off >>= 1) p += __shfl_xor(p, off, 64);
    if (lane == 0) {
        v_raw[node] = 1.f / (1.f + expf(-(p + b_att[0])));
    }
}

// ---------------- graph ranges via sorted-boundary detection (no atomics) ----
__global__ void k_bounds(const int* __restrict__ batch, int* __restrict__ gbound) {
    int n = blockIdx.x * blockDim.x + threadIdx.x;
    if (n >= N_NODES) return;
    int b = batch[n];
    int prev = (n == 0) ? -1 : batch[n - 1];
    for (int g = prev + 1; g <= b; ++g) gbound[g] = n;
    if (n == N_NODES - 1) {
        for (int g = b + 1; g <= NGRAPH; ++g) gbound[g] = N_NODES;
    }
}

// ---------------- readout + MLP head, one block per graph ----------------
__global__ void k_readout_mlp(const float* __restrict__ h, const float* __restrict__ v_raw,
        const int* __restrict__ gbound,
        const float* __restrict__ W1, const float* __restrict__ b1,
        const float* __restrict__ W2, const float* __restrict__ b2,
        const float* __restrict__ W3, const float* __restrict__ b3,
        float* __restrict__ out) {
    int g = blockIdx.x, t = threadIdx.x;
    int s = gbound[g], e = gbound[g + 1];
    __shared__ float red[256];

    // segment max of v
    float m = -3.402823466e38f;
    for (int n = s + t; n < e; n += 256) m = fmaxf(m, v_raw[n]);
    red[t] = m; __syncthreads();
    for (int off = 128; off >= 1; off >>= 1) {
        if (t < off) red[t] = fmaxf(red[t], red[t + off]);
        __syncthreads();
    }
    float vmax = red[0]; __syncthreads();

    // segment sum of exp(v - vmax)
    float ss = 0.f;
    for (int n = s + t; n < e; n += 256) ss += expf(v_raw[n] - vmax);
    red[t] = ss; __syncthreads();
    for (int off = 128; off >= 1; off >>= 1) {
        if (t < off) red[t] += red[t + off];
        __syncthreads();
    }
    float inv = 1.f / (red[0] + 1e-16f);
    __syncthreads();

    // gmp (segment max of h) and gsp (sum of v*h): 4 waves split nodes, lane=feature
    int wv = t >> 6, lane = t & 63;
    float gm = -3.402823466e38f, gs = 0.f;
    for (int n = s + wv; n < e; n += 4) {
        float hv = h[n * 64 + lane];
        float vn = expf(v_raw[n] - vmax) * inv;
        gm = fmaxf(gm, hv);
        gs += vn * hv;
    }
    __shared__ float pm[4][64], ps[4][64];
    pm[wv][lane] = gm; ps[wv][lane] = gs;
    __syncthreads();

    __shared__ float z[128];
    if (t < 64) {
        z[t] = fmaxf(fmaxf(pm[0][t], pm[1][t]), fmaxf(pm[2][t], pm[3][t]));
        z[64 + t] = ps[0][t] + ps[1][t] + ps[2][t] + ps[3][t];
    }
    __syncthreads();

    // MLP head
    __shared__ float z1[64];
    if (t < 64) {
        float a = b1[t];
#pragma unroll 8
        for (int k = 0; k < 128; ++k) a += z[k] * W1[k * 64 + t];
        z1[t] = fmaxf(a, 0.f);
    }
    __syncthreads();
    __shared__ float z2[32];
    if (t < 32) {
        float a = b2[t];
#pragma unroll 8
        for (int k = 0; k < 64; ++k) a += z1[k] * W2[k * 32 + t];
        z2[t] = fmaxf(a, 0.f);
    }
    __syncthreads();
    __shared__ float z3[8];
    if (t < 8) {
        float a = b3[t];
#pragma unroll
        for (int k = 0; k < 32; ++k) a += z2[k] * W3[k * 8 + t];
        z3[t] = a;
    }
    __syncthreads();
    if (t == 0) {
        float mx = z3[0];
#pragma unroll
        for (int j = 1; j < 8; ++j) mx = fmaxf(mx, z3[j]);
        float se = 0.f;
#pragma unroll
        for (int j = 0; j < 8; ++j) se += expf(z3[j] - mx);
        float lse = mx + logf(se);
#pragma unroll
        for (int j = 0; j < 8; ++j) out[g * 8 + j] = z3[j] - lse;
    }
}

extern "C" void kernel_launch(void* const* d_in, const int* in_sizes, int n_in,
                              void* d_out, int out_size, void* d_ws, size_t ws_size,
                              hipStream_t stream) {
    const float* x     = (const float*)d_in[0];
    const int*   edge  = (const int*)d_in[1];
    const int*   row   = edge;
    const int*   col   = edge + N_EDGES;
    const int*   batch = (const int*)d_in[2];
    const float* W_sgc = (const float*)d_in[3];
    const float* b_sgc = (const float*)d_in[4];
    const float* w_att = (const float*)d_in[5];
    const float* b_att = (const float*)d_in[6];
    const float* W1    = (const float*)d_in[7];
    const float* b1    = (const float*)d_in[8];
    const float* W2    = (const float*)d_in[9];
    const float* b2    = (const float*)d_in[10];
    const float* W3    = (const float*)d_in[11];
    const float* b3    = (const float*)d_in[12];
    float* out = (float*)d_out;

    char* p = (char*)d_ws;
    auto alloc = [&](size_t bytes) {
        char* r = p;
        p += (bytes + 255) & ~(size_t)255;
        return r;
    };
    int*   counts  = (int*)alloc((size_t)N_NODES * 4);
    int*   cursor  = (int*)alloc((size_t)N_NODES * 4);
    int*   gbound  = (int*)alloc((size_t)(NGRAPH + 1) * 4);
    int*   start   = (int*)alloc((size_t)N_NODES * 4);
    int*   partial = (int*)alloc((size_t)SCAN_NB * 4);
    int*   coff    = (int*)alloc((size_t)SCAN_NB * 4);
    float* dinv    = (float*)alloc((size_t)N_NODES * 4);
    float* vraw    = (float*)alloc((size_t)N_NODES * 4);
    float* h0      = (float*)alloc((size_t)N_NODES * 64 * 4);
    float* hA      = (float*)alloc((size_t)N_NODES * 64 * 4);
    float* hB      = (float*)alloc((size_t)N_NODES * 64 * 4);
    int2*  csr     = (int2*)alloc((size_t)N_EDGES * 8);

    // zero counts+cursor INCLUDING the 256B alloc padding (pointer difference,
    // not raw element count — 0xAA poison in the pad was the R2 OOB fault)
    hipMemsetAsync(counts, 0, (size_t)((char*)gbound - (char*)counts), stream);

    k_count<<<(N_EDGES + 255) / 256, 256, 0, stream>>>(row, counts);
    k_scan_part<<<SCAN_NB, 256, 0, stream>>>(counts, partial);
    k_scan_top<<<1, 64, 0, stream>>>(partial, coff);
    k_scan_final<<<SCAN_NB, 256, 0, stream>>>(counts, coff, start, dinv);
    k_scatter<<<(N_EDGES + 255) / 256, 256, 0, stream>>>(row, col, dinv, start, cursor, csr);
    k_h0<<<(N_NODES + 63) / 64, 256, 0, stream>>>(x, W_sgc, b_sgc, h0);
    k_hop<<<(N_NODES + 3) / 4, 256, 0, stream>>>(h0, h0, dinv, start, counts, csr, hA);
    k_hop<<<(N_NODES + 3) / 4, 256, 0, stream>>>(hA, h0, dinv, start, counts, csr, hB);
    k_hop_final<<<(N_NODES + 3) / 4, 256, 0, stream>>>(hB, h0, dinv, start, counts, csr,
                                                       w_att, b_att, hA, vraw);
    k_bounds<<<(N_NODES + 255) / 256, 256, 0, stream>>>(batch, gbound);
    k_readout_mlp<<<NGRAPH, 256, 0, stream>>>(hA, vraw, gbound,
                                              W1, b1, W2, b2, W3, b3, out);
}

// Round 4
// 371.861 us; speedup vs baseline: 1.9788x; 1.3575x over previous
//
#include <hip/hip_runtime.h>
#include <math.h>

#define N_NODES 100000
#define N_EDGES 1000000
#define NGRAPH 256

#define SCAN_CH 1024
#define SCAN_NB ((N_NODES + SCAN_CH - 1) / SCAN_CH)   // 98

typedef unsigned short ushort_t;

__device__ __forceinline__ ushort_t f2bf(float f) {   // round-to-nearest-even
    unsigned u = __float_as_uint(f);
    u += 0x7fffu + ((u >> 16) & 1u);
    return (ushort_t)(u >> 16);
}
__device__ __forceinline__ float bf2f(ushort_t u) {
    return __uint_as_float(((unsigned)u) << 16);
}

using frag_ab = __attribute__((ext_vector_type(8))) short;   // 8 bf16 = 4 VGPRs
using frag_cd = __attribute__((ext_vector_type(4))) float;   // 4 fp32

// ---------------- degree count ----------------
__global__ void k_count(const int* __restrict__ row, int* __restrict__ counts) {
    int e = blockIdx.x * blockDim.x + threadIdx.x;
    if (e < N_EDGES) atomicAdd(&counts[row[e]], 1);
}

// ---------------- 2-level exclusive scan ----------------
__global__ void k_scan_part(const int* __restrict__ counts, int* __restrict__ partial) {
    __shared__ int sd[256];
    int b = blockIdx.x, t = threadIdx.x;
    int base = b * SCAN_CH + t * 4;
    int s = 0;
#pragma unroll
    for (int j = 0; j < 4; ++j) {
        int idx = base + j;
        if (idx < N_NODES) s += counts[idx];
    }
    sd[t] = s; __syncthreads();
    for (int off = 128; off >= 1; off >>= 1) {
        if (t < off) sd[t] += sd[t + off];
        __syncthreads();
    }
    if (t == 0) partial[b] = sd[0];
}

__global__ void k_scan_top(const int* __restrict__ partial, int* __restrict__ coff) {
    if (threadIdx.x == 0 && blockIdx.x == 0) {
        int run = 0;
        for (int b = 0; b < SCAN_NB; ++b) { coff[b] = run; run += partial[b]; }
    }
}

__global__ void k_scan_final(const int* __restrict__ counts, const int* __restrict__ coff,
                             int* __restrict__ start, float* __restrict__ dinv) {
    __shared__ int sd[256];
    int b = blockIdx.x, t = threadIdx.x;
    int base = b * SCAN_CH + t * 4;
    int c[4]; int s = 0;
#pragma unroll
    for (int j = 0; j < 4; ++j) {
        int idx = base + j;
        c[j] = (idx < N_NODES) ? counts[idx] : 0;
        s += c[j];
    }
    sd[t] = s; __syncthreads();
    for (int off = 1; off < 256; off <<= 1) {
        int v = (t >= off) ? sd[t - off] : 0;
        __syncthreads();
        sd[t] += v;
        __syncthreads();
    }
    int run = sd[t] - s + coff[b];
#pragma unroll
    for (int j = 0; j < 4; ++j) {
        int idx = base + j;
        if (idx < N_NODES) {
            start[idx] = run;
            run += c[j];
            dinv[idx] = rsqrtf((float)(c[j] + 1));
        }
    }
}

// ---------------- CSR scatter ----------------
__global__ void k_scatter(const int* __restrict__ row, const int* __restrict__ col,
                          const float* __restrict__ dinv, const int* __restrict__ start,
                          int* __restrict__ cursor, int2* __restrict__ csr) {
    int e = blockIdx.x * blockDim.x + threadIdx.x;
    if (e >= N_EDGES) return;
    int r = row[e], c = col[e];
    float w = 0.5f * dinv[r] * dinv[c];   // (1-alpha) * norm folded in
    int p = start[r] + atomicAdd(&cursor[r], 1);
    csr[p] = make_int2(c, __float_as_int(w));
}

// ---------------- h0 = x @ W_sgc + b_sgc via bf16 MFMA, bf16 output ---------
// one wave per 16-row tile; N_NODES = 6250 * 16 exactly.
__global__ __launch_bounds__(256) void k_h0(const float* __restrict__ x,
        const float* __restrict__ W, const float* __restrict__ bias,
        ushort_t* __restrict__ h0b) {
    int wid = (blockIdx.x * 256 + (int)threadIdx.x) >> 6;
    int lane = threadIdx.x & 63;
    if (wid >= N_NODES / 16) return;
    int row0 = wid * 16;
    int m = lane & 15, q = lane >> 4;   // q in [0,4)

    // B fragments: bfr[ks][nt][j] = W[ks*32 + q*8 + j][nt*16 + m]  (W is 64x64, L2-hot)
    frag_ab bfr[2][4];
#pragma unroll
    for (int ks = 0; ks < 2; ++ks)
#pragma unroll
        for (int nt = 0; nt < 4; ++nt)
#pragma unroll
            for (int j = 0; j < 8; ++j)
                bfr[ks][nt][j] = (short)f2bf(W[(ks * 32 + q * 8 + j) * 64 + nt * 16 + m]);

    // A fragments: afr[ks][j] = x[row0+m][ks*32 + q*8 + j]
    frag_ab afr[2];
#pragma unroll
    for (int ks = 0; ks < 2; ++ks) {
        const float4* xp = (const float4*)(x + (size_t)(row0 + m) * 64 + ks * 32 + q * 8);
        float4 v0 = xp[0], v1 = xp[1];
        afr[ks][0] = (short)f2bf(v0.x); afr[ks][1] = (short)f2bf(v0.y);
        afr[ks][2] = (short)f2bf(v0.z); afr[ks][3] = (short)f2bf(v0.w);
        afr[ks][4] = (short)f2bf(v1.x); afr[ks][5] = (short)f2bf(v1.y);
        afr[ks][6] = (short)f2bf(v1.z); afr[ks][7] = (short)f2bf(v1.w);
    }

    frag_cd acc[4];
#pragma unroll
    for (int nt = 0; nt < 4; ++nt) acc[nt] = (frag_cd){0.f, 0.f, 0.f, 0.f};
#pragma unroll
    for (int ks = 0; ks < 2; ++ks)
#pragma unroll
        for (int nt = 0; nt < 4; ++nt)
            acc[nt] = __builtin_amdgcn_mfma_f32_16x16x32_bf16(afr[ks], bfr[ks][nt], acc[nt], 0, 0, 0);

    // C/D layout: col = lane&15, row = (lane>>4)*4 + reg   [m89-verified]
#pragma unroll
    for (int nt = 0; nt < 4; ++nt) {
        int cc = nt * 16 + m;
        float bl = bias[cc];
#pragma unroll
        for (int r = 0; r < 4; ++r) {
            int rr = row0 + q * 4 + r;
            h0b[(size_t)rr * 64 + cc] = f2bf(acc[nt][r] + bl);
        }
    }
}

// ---------------- propagation hop (bf16 gather, 8-wide MLP) ----------------
__device__ __forceinline__ float hop_acc(int node, int lane,
        const ushort_t* __restrict__ hb_in, const ushort_t* __restrict__ h0b,
        const float* __restrict__ dinv, const int* __restrict__ start,
        const int* __restrict__ counts, const int2* __restrict__ csr) {
    float di = dinv[node];
    float acc = 0.5f * di * di * bf2f(hb_in[(size_t)node * 64 + lane])
              + 0.5f * bf2f(h0b[(size_t)node * 64 + lane]);
    int s = start[node], cnt = counts[node];
    int j = 0;
    for (; j + 8 <= cnt; j += 8) {
        int2 e0 = csr[s + j],     e1 = csr[s + j + 1];
        int2 e2 = csr[s + j + 2], e3 = csr[s + j + 3];
        int2 e4 = csr[s + j + 4], e5 = csr[s + j + 5];
        int2 e6 = csr[s + j + 6], e7 = csr[s + j + 7];
        ushort_t u0 = hb_in[(size_t)e0.x * 64 + lane];
        ushort_t u1 = hb_in[(size_t)e1.x * 64 + lane];
        ushort_t u2 = hb_in[(size_t)e2.x * 64 + lane];
        ushort_t u3 = hb_in[(size_t)e3.x * 64 + lane];
        ushort_t u4 = hb_in[(size_t)e4.x * 64 + lane];
        ushort_t u5 = hb_in[(size_t)e5.x * 64 + lane];
        ushort_t u6 = hb_in[(size_t)e6.x * 64 + lane];
        ushort_t u7 = hb_in[(size_t)e7.x * 64 + lane];
        acc += __int_as_float(e0.y) * bf2f(u0);
        acc += __int_as_float(e1.y) * bf2f(u1);
        acc += __int_as_float(e2.y) * bf2f(u2);
        acc += __int_as_float(e3.y) * bf2f(u3);
        acc += __int_as_float(e4.y) * bf2f(u4);
        acc += __int_as_float(e5.y) * bf2f(u5);
        acc += __int_as_float(e6.y) * bf2f(u6);
        acc += __int_as_float(e7.y) * bf2f(u7);
    }
    for (; j + 2 <= cnt; j += 2) {
        int2 e0 = csr[s + j], e1 = csr[s + j + 1];
        ushort_t u0 = hb_in[(size_t)e0.x * 64 + lane];
        ushort_t u1 = hb_in[(size_t)e1.x * 64 + lane];
        acc += __int_as_float(e0.y) * bf2f(u0);
        acc += __int_as_float(e1.y) * bf2f(u1);
    }
    if (j < cnt) {
        int2 e0 = csr[s + j];
        acc += __int_as_float(e0.y) * bf2f(hb_in[(size_t)e0.x * 64 + lane]);
    }
    return acc;
}

__global__ void k_hop(const ushort_t* __restrict__ hb_in, const ushort_t* __restrict__ h0b,
                      const float* __restrict__ dinv, const int* __restrict__ start,
                      const int* __restrict__ counts, const int2* __restrict__ csr,
                      ushort_t* __restrict__ hb_out) {
    int node = blockIdx.x * 4 + ((int)threadIdx.x >> 6);
    int lane = threadIdx.x & 63;
    if (node >= N_NODES) return;
    float acc = hop_acc(node, lane, hb_in, h0b, dinv, start, counts, csr);
    hb_out[(size_t)node * 64 + lane] = f2bf(acc);
}

// final hop fused with relu + attention gate dot product
__global__ void k_hop_final(const ushort_t* __restrict__ hb_in, const ushort_t* __restrict__ h0b,
                            const float* __restrict__ dinv, const int* __restrict__ start,
                            const int* __restrict__ counts, const int2* __restrict__ csr,
                            const float* __restrict__ w_att, const float* __restrict__ b_att,
                            ushort_t* __restrict__ hb_out, float* __restrict__ v_raw) {
    int node = blockIdx.x * 4 + ((int)threadIdx.x >> 6);
    int lane = threadIdx.x & 63;
    if (node >= N_NODES) return;
    float acc = hop_acc(node, lane, hb_in, h0b, dinv, start, counts, csr);
    float hv = fmaxf(acc, 0.f);
    hb_out[(size_t)node * 64 + lane] = f2bf(hv);
    float p = hv * w_att[lane];
#pragma unroll
    for (int off = 32; off >= 1; off >>= 1) p += __shfl_xor(p, off, 64);
    if (lane == 0) {
        v_raw[node] = 1.f / (1.f + expf(-(p + b_att[0])));
    }
}

// ---------------- graph ranges via sorted-boundary detection (no atomics) ----
__global__ void k_bounds(const int* __restrict__ batch, int* __restrict__ gbound) {
    int n = blockIdx.x * blockDim.x + threadIdx.x;
    if (n >= N_NODES) return;
    int b = batch[n];
    int prev = (n == 0) ? -1 : batch[n - 1];
    for (int g = prev + 1; g <= b; ++g) gbound[g] = n;
    if (n == N_NODES - 1) {
        for (int g = b + 1; g <= NGRAPH; ++g) gbound[g] = N_NODES;
    }
}

// ---------------- readout + MLP head, one block per graph ----------------
__global__ void k_readout_mlp(const ushort_t* __restrict__ hb, const float* __restrict__ v_raw,
        const int* __restrict__ gbound,
        const float* __restrict__ W1, const float* __restrict__ b1,
        const float* __restrict__ W2, const float* __restrict__ b2,
        const float* __restrict__ W3, const float* __restrict__ b3,
        float* __restrict__ out) {
    int g = blockIdx.x, t = threadIdx.x;
    int s = gbound[g], e = gbound[g + 1];
    __shared__ float red[256];

    // segment max of v
    float m = -3.402823466e38f;
    for (int n = s + t; n < e; n += 256) m = fmaxf(m, v_raw[n]);
    red[t] = m; __syncthreads();
    for (int off = 128; off >= 1; off >>= 1) {
        if (t < off) red[t] = fmaxf(red[t], red[t + off]);
        __syncthreads();
    }
    float vmax = red[0]; __syncthreads();

    // segment sum of exp(v - vmax)
    float ss = 0.f;
    for (int n = s + t; n < e; n += 256) ss += expf(v_raw[n] - vmax);
    red[t] = ss; __syncthreads();
    for (int off = 128; off >= 1; off >>= 1) {
        if (t < off) red[t] += red[t + off];
        __syncthreads();
    }
    float inv = 1.f / (red[0] + 1e-16f);
    __syncthreads();

    // gmp (segment max of h) and gsp (sum of v*h): 4 waves split nodes, lane=feature
    int wv = t >> 6, lane = t & 63;
    float gm = -3.402823466e38f, gs = 0.f;
    for (int n = s + wv; n < e; n += 4) {
        float hv = bf2f(hb[(size_t)n * 64 + lane]);
        float vn = expf(v_raw[n] - vmax) * inv;
        gm = fmaxf(gm, hv);
        gs += vn * hv;
    }
    __shared__ float pm[4][64], ps[4][64];
    pm[wv][lane] = gm; ps[wv][lane] = gs;
    __syncthreads();

    __shared__ float z[128];
    if (t < 64) {
        z[t] = fmaxf(fmaxf(pm[0][t], pm[1][t]), fmaxf(pm[2][t], pm[3][t]));
        z[64 + t] = ps[0][t] + ps[1][t] + ps[2][t] + ps[3][t];
    }
    __syncthreads();

    // MLP head
    __shared__ float z1[64];
    if (t < 64) {
        float a = b1[t];
#pragma unroll 8
        for (int k = 0; k < 128; ++k) a += z[k] * W1[k * 64 + t];
        z1[t] = fmaxf(a, 0.f);
    }
    __syncthreads();
    __shared__ float z2[32];
    if (t < 32) {
        float a = b2[t];
#pragma unroll 8
        for (int k = 0; k < 64; ++k) a += z1[k] * W2[k * 32 + t];
        z2[t] = fmaxf(a, 0.f);
    }
    __syncthreads();
    __shared__ float z3[8];
    if (t < 8) {
        float a = b3[t];
#pragma unroll
        for (int k = 0; k < 32; ++k) a += z2[k] * W3[k * 8 + t];
        z3[t] = a;
    }
    __syncthreads();
    if (t == 0) {
        float mx = z3[0];
#pragma unroll
        for (int j = 1; j < 8; ++j) mx = fmaxf(mx, z3[j]);
        float se = 0.f;
#pragma unroll
        for (int j = 0; j < 8; ++j) se += expf(z3[j] - mx);
        float lse = mx + logf(se);
#pragma unroll
        for (int j = 0; j < 8; ++j) out[g * 8 + j] = z3[j] - lse;
    }
}

extern "C" void kernel_launch(void* const* d_in, const int* in_sizes, int n_in,
                              void* d_out, int out_size, void* d_ws, size_t ws_size,
                              hipStream_t stream) {
    const float* x     = (const float*)d_in[0];
    const int*   edge  = (const int*)d_in[1];
    const int*   row   = edge;
    const int*   col   = edge + N_EDGES;
    const int*   batch = (const int*)d_in[2];
    const float* W_sgc = (const float*)d_in[3];
    const float* b_sgc = (const float*)d_in[4];
    const float* w_att = (const float*)d_in[5];
    const float* b_att = (const float*)d_in[6];
    const float* W1    = (const float*)d_in[7];
    const float* b1    = (const float*)d_in[8];
    const float* W2    = (const float*)d_in[9];
    const float* b2    = (const float*)d_in[10];
    const float* W3    = (const float*)d_in[11];
    const float* b3    = (const float*)d_in[12];
    float* out = (float*)d_out;

    char* p = (char*)d_ws;
    auto alloc = [&](size_t bytes) {
        char* r = p;
        p += (bytes + 255) & ~(size_t)255;
        return r;
    };
    int*      counts  = (int*)alloc((size_t)N_NODES * 4);
    int*      cursor  = (int*)alloc((size_t)N_NODES * 4);
    int*      gbound  = (int*)alloc((size_t)(NGRAPH + 1) * 4);
    int*      start   = (int*)alloc((size_t)N_NODES * 4);
    int*      partial = (int*)alloc((size_t)SCAN_NB * 4);
    int*      coff    = (int*)alloc((size_t)SCAN_NB * 4);
    float*    dinv    = (float*)alloc((size_t)N_NODES * 4);
    float*    vraw    = (float*)alloc((size_t)N_NODES * 4);
    ushort_t* h0b     = (ushort_t*)alloc((size_t)N_NODES * 64 * 2);
    ushort_t* hAb     = (ushort_t*)alloc((size_t)N_NODES * 64 * 2);
    ushort_t* hBb     = (ushort_t*)alloc((size_t)N_NODES * 64 * 2);
    int2*     csr     = (int2*)alloc((size_t)N_EDGES * 8);

    // zero counts+cursor INCLUDING the 256B alloc padding (pointer difference —
    // 0xAA poison in the pad was the R2 OOB fault)
    hipMemsetAsync(counts, 0, (size_t)((char*)gbound - (char*)counts), stream);

    k_count<<<(N_EDGES + 255) / 256, 256, 0, stream>>>(row, counts);
    k_scan_part<<<SCAN_NB, 256, 0, stream>>>(counts, partial);
    k_scan_top<<<1, 64, 0, stream>>>(partial, coff);
    k_scan_final<<<SCAN_NB, 256, 0, stream>>>(counts, coff, start, dinv);
    k_scatter<<<(N_EDGES + 255) / 256, 256, 0, stream>>>(row, col, dinv, start, cursor, csr);
    k_h0<<<(N_NODES / 16 + 3) / 4, 256, 0, stream>>>(x, W_sgc, b_sgc, h0b);
    k_hop<<<(N_NODES + 3) / 4, 256, 0, stream>>>(h0b, h0b, dinv, start, counts, csr, hAb);
    k_hop<<<(N_NODES + 3) / 4, 256, 0, stream>>>(hAb, h0b, dinv, start, counts, csr, hBb);
    k_hop_final<<<(N_NODES + 3) / 4, 256, 0, stream>>>(hBb, h0b, dinv, start, counts, csr,
                                                       w_att, b_att, hAb, vraw);
    k_bounds<<<(N_NODES + 255) / 256, 256, 0, stream>>>(batch, gbound);
    k_readout_mlp<<<NGRAPH, 256, 0, stream>>>(hAb, vraw, gbound,
                                              W1, b1, W2, b2, W3, b3, out);
}

// Round 5
// 339.154 us; speedup vs baseline: 2.1696x; 1.0964x over previous
//
#include <hip/hip_runtime.h>
#include <math.h>

#define N_NODES 100000
#define N_EDGES 1000000
#define NGRAPH 256

#define SCAN_CH 1024
#define SCAN_NB ((N_NODES + SCAN_CH - 1) / SCAN_CH)   // 98

typedef unsigned short ushort_t;

__device__ __forceinline__ ushort_t f2bf(float f) {   // round-to-nearest-even
    unsigned u = __float_as_uint(f);
    u += 0x7fffu + ((u >> 16) & 1u);
    return (ushort_t)(u >> 16);
}
__device__ __forceinline__ float bf2f(ushort_t u) {
    return __uint_as_float(((unsigned)u) << 16);
}
__device__ __forceinline__ float bf_lo(unsigned u) {  // feature 2l (low ushort)
    return __uint_as_float(u << 16);
}
__device__ __forceinline__ float bf_hi(unsigned u) {  // feature 2l+1 (high ushort)
    return __uint_as_float(u & 0xffff0000u);
}

using frag_ab = __attribute__((ext_vector_type(8))) short;   // 8 bf16 = 4 VGPRs
using frag_cd = __attribute__((ext_vector_type(4))) float;   // 4 fp32

// ---------------- degree count ----------------
__global__ void k_count(const int* __restrict__ row, int* __restrict__ counts) {
    int e = blockIdx.x * blockDim.x + threadIdx.x;
    if (e < N_EDGES) atomicAdd(&counts[row[e]], 1);
}

// ---------------- 2-level exclusive scan ----------------
__global__ void k_scan_part(const int* __restrict__ counts, int* __restrict__ partial) {
    __shared__ int sd[256];
    int b = blockIdx.x, t = threadIdx.x;
    int base = b * SCAN_CH + t * 4;
    int s = 0;
#pragma unroll
    for (int j = 0; j < 4; ++j) {
        int idx = base + j;
        if (idx < N_NODES) s += counts[idx];
    }
    sd[t] = s; __syncthreads();
    for (int off = 128; off >= 1; off >>= 1) {
        if (t < off) sd[t] += sd[t + off];
        __syncthreads();
    }
    if (t == 0) partial[b] = sd[0];
}

__global__ void k_scan_top(const int* __restrict__ partial, int* __restrict__ coff) {
    if (threadIdx.x == 0 && blockIdx.x == 0) {
        int run = 0;
        for (int b = 0; b < SCAN_NB; ++b) { coff[b] = run; run += partial[b]; }
    }
}

__global__ void k_scan_final(const int* __restrict__ counts, const int* __restrict__ coff,
                             int* __restrict__ start, float* __restrict__ dinv) {
    __shared__ int sd[256];
    int b = blockIdx.x, t = threadIdx.x;
    int base = b * SCAN_CH + t * 4;
    int c[4]; int s = 0;
#pragma unroll
    for (int j = 0; j < 4; ++j) {
        int idx = base + j;
        c[j] = (idx < N_NODES) ? counts[idx] : 0;
        s += c[j];
    }
    sd[t] = s; __syncthreads();
    for (int off = 1; off < 256; off <<= 1) {
        int v = (t >= off) ? sd[t - off] : 0;
        __syncthreads();
        sd[t] += v;
        __syncthreads();
    }
    int run = sd[t] - s + coff[b];
#pragma unroll
    for (int j = 0; j < 4; ++j) {
        int idx = base + j;
        if (idx < N_NODES) {
            start[idx] = run;
            run += c[j];
            dinv[idx] = rsqrtf((float)(c[j] + 1));
        }
    }
}

// ---------------- CSR scatter: col only (4B), weight recomputed in hop ------
__global__ void k_scatter(const int* __restrict__ row, const int* __restrict__ col,
                          const int* __restrict__ start,
                          int* __restrict__ cursor, unsigned* __restrict__ csr4) {
    int e = blockIdx.x * blockDim.x + threadIdx.x;
    if (e >= N_EDGES) return;
    int r = row[e];
    int p = start[r] + atomicAdd(&cursor[r], 1);
    csr4[p] = (unsigned)col[e];
}

// ---------------- h0 = x @ W_sgc + b_sgc via bf16 MFMA, bf16 output ---------
// one wave per 16-row tile; N_NODES = 6250 * 16 exactly.
__global__ __launch_bounds__(256) void k_h0(const float* __restrict__ x,
        const float* __restrict__ W, const float* __restrict__ bias,
        ushort_t* __restrict__ h0b) {
    int wid = (blockIdx.x * 256 + (int)threadIdx.x) >> 6;
    int lane = threadIdx.x & 63;
    if (wid >= N_NODES / 16) return;
    int row0 = wid * 16;
    int m = lane & 15, q = lane >> 4;   // q in [0,4)

    // B fragments: bfr[ks][nt][j] = W[ks*32 + q*8 + j][nt*16 + m]
    frag_ab bfr[2][4];
#pragma unroll
    for (int ks = 0; ks < 2; ++ks)
#pragma unroll
        for (int nt = 0; nt < 4; ++nt)
#pragma unroll
            for (int j = 0; j < 8; ++j)
                bfr[ks][nt][j] = (short)f2bf(W[(ks * 32 + q * 8 + j) * 64 + nt * 16 + m]);

    // A fragments: afr[ks][j] = x[row0+m][ks*32 + q*8 + j]
    frag_ab afr[2];
#pragma unroll
    for (int ks = 0; ks < 2; ++ks) {
        const float4* xp = (const float4*)(x + (size_t)(row0 + m) * 64 + ks * 32 + q * 8);
        float4 v0 = xp[0], v1 = xp[1];
        afr[ks][0] = (short)f2bf(v0.x); afr[ks][1] = (short)f2bf(v0.y);
        afr[ks][2] = (short)f2bf(v0.z); afr[ks][3] = (short)f2bf(v0.w);
        afr[ks][4] = (short)f2bf(v1.x); afr[ks][5] = (short)f2bf(v1.y);
        afr[ks][6] = (short)f2bf(v1.z); afr[ks][7] = (short)f2bf(v1.w);
    }

    frag_cd acc[4];
#pragma unroll
    for (int nt = 0; nt < 4; ++nt) acc[nt] = (frag_cd){0.f, 0.f, 0.f, 0.f};
#pragma unroll
    for (int ks = 0; ks < 2; ++ks)
#pragma unroll
        for (int nt = 0; nt < 4; ++nt)
            acc[nt] = __builtin_amdgcn_mfma_f32_16x16x32_bf16(afr[ks], bfr[ks][nt], acc[nt], 0, 0, 0);

    // C/D layout: col = lane&15, row = (lane>>4)*4 + reg   [m89-verified]
#pragma unroll
    for (int nt = 0; nt < 4; ++nt) {
        int cc = nt * 16 + m;
        float bl = bias[cc];
#pragma unroll
        for (int r = 0; r < 4; ++r) {
            int rr = row0 + q * 4 + r;
            h0b[(size_t)rr * 64 + cc] = f2bf(acc[nt][r] + bl);
        }
    }
}

// ---------------- propagation hop: 2 nodes/wave, bf16x2 per lane ------------
// lane l (0..31 within half-wave) handles features 2l, 2l+1 of its node.
__device__ __forceinline__ void hop_acc2(int node, int l,
        const unsigned* __restrict__ hb_in, const unsigned* __restrict__ h0b,
        const float* __restrict__ dinv, const int* __restrict__ start,
        const int* __restrict__ counts, const unsigned* __restrict__ csr4,
        float& a0, float& a1) {
    float di = dinv[node];
    unsigned us = hb_in[node * 32 + l];
    unsigned u0 = h0b[node * 32 + l];
    float self = 0.5f * di * di;
    a0 = self * bf_lo(us) + 0.5f * bf_lo(u0);
    a1 = self * bf_hi(us) + 0.5f * bf_hi(u0);
    float C = 0.5f * di;
    int s = start[node], cnt = counts[node];
    int j = 0;
    for (; j + 4 <= cnt; j += 4) {   // divergent trip count across halves: exec-masked
        unsigned c0 = csr4[s + j],     c1 = csr4[s + j + 1];
        unsigned c2 = csr4[s + j + 2], c3 = csr4[s + j + 3];
        float w0 = C * dinv[c0], w1 = C * dinv[c1];
        float w2 = C * dinv[c2], w3 = C * dinv[c3];
        unsigned v0 = hb_in[c0 * 32 + l];
        unsigned v1 = hb_in[c1 * 32 + l];
        unsigned v2 = hb_in[c2 * 32 + l];
        unsigned v3 = hb_in[c3 * 32 + l];
        a0 += w0 * bf_lo(v0); a1 += w0 * bf_hi(v0);
        a0 += w1 * bf_lo(v1); a1 += w1 * bf_hi(v1);
        a0 += w2 * bf_lo(v2); a1 += w2 * bf_hi(v2);
        a0 += w3 * bf_lo(v3); a1 += w3 * bf_hi(v3);
    }
    for (; j < cnt; ++j) {
        unsigned c0 = csr4[s + j];
        float w0 = C * dinv[c0];
        unsigned v0 = hb_in[c0 * 32 + l];
        a0 += w0 * bf_lo(v0); a1 += w0 * bf_hi(v0);
    }
}

__global__ void k_hop(const unsigned* __restrict__ hb_in, const unsigned* __restrict__ h0b,
                      const float* __restrict__ dinv, const int* __restrict__ start,
                      const int* __restrict__ counts, const unsigned* __restrict__ csr4,
                      unsigned* __restrict__ hb_out) {
    int node = blockIdx.x * 8 + ((int)threadIdx.x >> 5);   // N_NODES % 8 == 0
    int l = threadIdx.x & 31;
    float a0, a1;
    hop_acc2(node, l, hb_in, h0b, dinv, start, counts, csr4, a0, a1);
    hb_out[node * 32 + l] = ((unsigned)f2bf(a1) << 16) | (unsigned)f2bf(a0);
}

// final hop fused with relu + attention gate dot product
__global__ void k_hop_final(const unsigned* __restrict__ hb_in, const unsigned* __restrict__ h0b,
                            const float* __restrict__ dinv, const int* __restrict__ start,
                            const int* __restrict__ counts, const unsigned* __restrict__ csr4,
                            const float* __restrict__ w_att, const float* __restrict__ b_att,
                            unsigned* __restrict__ hb_out, float* __restrict__ v_raw) {
    int node = blockIdx.x * 8 + ((int)threadIdx.x >> 5);
    int l = threadIdx.x & 31;
    float a0, a1;
    hop_acc2(node, l, hb_in, h0b, dinv, start, counts, csr4, a0, a1);
    float h0v = fmaxf(a0, 0.f), h1v = fmaxf(a1, 0.f);
    hb_out[node * 32 + l] = ((unsigned)f2bf(h1v) << 16) | (unsigned)f2bf(h0v);
    float2 wa = *(const float2*)(w_att + 2 * l);
    float p = h0v * wa.x + h1v * wa.y;
#pragma unroll
    for (int off = 16; off >= 1; off >>= 1) p += __shfl_xor(p, off, 64);  // stays in half
    if (l == 0) {
        v_raw[node] = 1.f / (1.f + expf(-(p + b_att[0])));
    }
}

// ---------------- graph ranges via sorted-boundary detection (no atomics) ----
__global__ void k_bounds(const int* __restrict__ batch, int* __restrict__ gbound) {
    int n = blockIdx.x * blockDim.x + threadIdx.x;
    if (n >= N_NODES) return;
    int b = batch[n];
    int prev = (n == 0) ? -1 : batch[n - 1];
    for (int g = prev + 1; g <= b; ++g) gbound[g] = n;
    if (n == N_NODES - 1) {
        for (int g = b + 1; g <= NGRAPH; ++g) gbound[g] = N_NODES;
    }
}

// ---------------- readout + MLP head, one block per graph ----------------
__global__ void k_readout_mlp(const ushort_t* __restrict__ hb, const float* __restrict__ v_raw,
        const int* __restrict__ gbound,
        const float* __restrict__ W1, const float* __restrict__ b1,
        const float* __restrict__ W2, const float* __restrict__ b2,
        const float* __restrict__ W3, const float* __restrict__ b3,
        float* __restrict__ out) {
    int g = blockIdx.x, t = threadIdx.x;
    int s = gbound[g], e = gbound[g + 1];
    __shared__ float red[256];

    // segment max of v
    float m = -3.402823466e38f;
    for (int n = s + t; n < e; n += 256) m = fmaxf(m, v_raw[n]);
    red[t] = m; __syncthreads();
    for (int off = 128; off >= 1; off >>= 1) {
        if (t < off) red[t] = fmaxf(red[t], red[t + off]);
        __syncthreads();
    }
    float vmax = red[0]; __syncthreads();

    // segment sum of exp(v - vmax)
    float ss = 0.f;
    for (int n = s + t; n < e; n += 256) ss += expf(v_raw[n] - vmax);
    red[t] = ss; __syncthreads();
    for (int off = 128; off >= 1; off >>= 1) {
        if (t < off) red[t] += red[t + off];
        __syncthreads();
    }
    float inv = 1.f / (red[0] + 1e-16f);
    __syncthreads();

    // gmp (segment max of h) and gsp (sum of v*h): 4 waves split nodes, lane=feature
    int wv = t >> 6, lane = t & 63;
    float gm = -3.402823466e38f, gs = 0.f;
    for (int n = s + wv; n < e; n += 4) {
        float hv = bf2f(hb[(size_t)n * 64 + lane]);
        float vn = expf(v_raw[n] - vmax) * inv;
        gm = fmaxf(gm, hv);
        gs += vn * hv;
    }
    __shared__ float pm[4][64], ps[4][64];
    pm[wv][lane] = gm; ps[wv][lane] = gs;
    __syncthreads();

    __shared__ float z[128];
    if (t < 64) {
        z[t] = fmaxf(fmaxf(pm[0][t], pm[1][t]), fmaxf(pm[2][t], pm[3][t]));
        z[64 + t] = ps[0][t] + ps[1][t] + ps[2][t] + ps[3][t];
    }
    __syncthreads();

    // MLP head
    __shared__ float z1[64];
    if (t < 64) {
        float a = b1[t];
#pragma unroll 8
        for (int k = 0; k < 128; ++k) a += z[k] * W1[k * 64 + t];
        z1[t] = fmaxf(a, 0.f);
    }
    __syncthreads();
    __shared__ float z2[32];
    if (t < 32) {
        float a = b2[t];
#pragma unroll 8
        for (int k = 0; k < 64; ++k) a += z1[k] * W2[k * 32 + t];
        z2[t] = fmaxf(a, 0.f);
    }
    __syncthreads();
    __shared__ float z3[8];
    if (t < 8) {
        float a = b3[t];
#pragma unroll
        for (int k = 0; k < 32; ++k) a += z2[k] * W3[k * 8 + t];
        z3[t] = a;
    }
    __syncthreads();
    if (t == 0) {
        float mx = z3[0];
#pragma unroll
        for (int j = 1; j < 8; ++j) mx = fmaxf(mx, z3[j]);
        float se = 0.f;
#pragma unroll
        for (int j = 0; j < 8; ++j) se += expf(z3[j] - mx);
        float lse = mx + logf(se);
#pragma unroll
        for (int j = 0; j < 8; ++j) out[g * 8 + j] = z3[j] - lse;
    }
}

extern "C" void kernel_launch(void* const* d_in, const int* in_sizes, int n_in,
                              void* d_out, int out_size, void* d_ws, size_t ws_size,
                              hipStream_t stream) {
    const float* x     = (const float*)d_in[0];
    const int*   edge  = (const int*)d_in[1];
    const int*   row   = edge;
    const int*   col   = edge + N_EDGES;
    const int*   batch = (const int*)d_in[2];
    const float* W_sgc = (const float*)d_in[3];
    const float* b_sgc = (const float*)d_in[4];
    const float* w_att = (const float*)d_in[5];
    const float* b_att = (const float*)d_in[6];
    const float* W1    = (const float*)d_in[7];
    const float* b1    = (const float*)d_in[8];
    const float* W2    = (const float*)d_in[9];
    const float* b2    = (const float*)d_in[10];
    const float* W3    = (const float*)d_in[11];
    const float* b3    = (const float*)d_in[12];
    float* out = (float*)d_out;

    char* p = (char*)d_ws;
    auto alloc = [&](size_t bytes) {
        char* r = p;
        p += (bytes + 255) & ~(size_t)255;
        return r;
    };
    int*      counts  = (int*)alloc((size_t)N_NODES * 4);
    int*      cursor  = (int*)alloc((size_t)N_NODES * 4);
    int*      gbound  = (int*)alloc((size_t)(NGRAPH + 1) * 4);
    int*      start   = (int*)alloc((size_t)N_NODES * 4);
    int*      partial = (int*)alloc((size_t)SCAN_NB * 4);
    int*      coff    = (int*)alloc((size_t)SCAN_NB * 4);
    float*    dinv    = (float*)alloc((size_t)N_NODES * 4);
    float*    vraw    = (float*)alloc((size_t)N_NODES * 4);
    ushort_t* h0b     = (ushort_t*)alloc((size_t)N_NODES * 64 * 2);
    ushort_t* hAb     = (ushort_t*)alloc((size_t)N_NODES * 64 * 2);
    ushort_t* hBb     = (ushort_t*)alloc((size_t)N_NODES * 64 * 2);
    unsigned* csr4    = (unsigned*)alloc((size_t)N_EDGES * 4);

    // zero counts+cursor INCLUDING the 256B alloc padding (pointer difference —
    // 0xAA poison in the pad was the R2 OOB fault)
    hipMemsetAsync(counts, 0, (size_t)((char*)gbound - (char*)counts), stream);

    k_count<<<(N_EDGES + 255) / 256, 256, 0, stream>>>(row, counts);
    k_scan_part<<<SCAN_NB, 256, 0, stream>>>(counts, partial);
    k_scan_top<<<1, 64, 0, stream>>>(partial, coff);
    k_scan_final<<<SCAN_NB, 256, 0, stream>>>(counts, coff, start, dinv);
    k_scatter<<<(N_EDGES + 255) / 256, 256, 0, stream>>>(row, col, start, cursor, csr4);
    k_h0<<<(N_NODES / 16 + 3) / 4, 256, 0, stream>>>(x, W_sgc, b_sgc, h0b);
    k_hop<<<N_NODES / 8, 256, 0, stream>>>((const unsigned*)h0b, (const unsigned*)h0b,
                                           dinv, start, counts, csr4, (unsigned*)hAb);
    k_hop<<<N_NODES / 8, 256, 0, stream>>>((const unsigned*)hAb, (const unsigned*)h0b,
                                           dinv, start, counts, csr4, (unsigned*)hBb);
    k_hop_final<<<N_NODES / 8, 256, 0, stream>>>((const unsigned*)hBb, (const unsigned*)h0b,
                                                 dinv, start, counts, csr4,
                                                 w_att, b_att, (unsigned*)hAb, vraw);
    k_bounds<<<(N_NODES + 255) / 256, 256, 0, stream>>>(batch, gbound);
    k_readout_mlp<<<NGRAPH, 256, 0, stream>>>(hAb, vraw, gbound,
                                              W1, b1, W2, b2, W3, b3, out);
}

// Round 6
// 271.743 us; speedup vs baseline: 2.7078x; 1.2481x over previous
//
#include <hip/hip_runtime.h>
#include <math.h>

#define N_NODES 100000
#define N_EDGES 1000000
#define NGRAPH 256

#define NBUCK 196          // ceil(100000 / 512)
#define BUCKN 512
#define BUCKCAP 8192       // max edges/bucket (mean ~5120, sigma ~71 -> huge margin)
#define EPB 4096           // edges per S1 block

typedef unsigned short ushort_t;

__device__ __forceinline__ ushort_t f2bf(float f) {   // round-to-nearest-even
    unsigned u = __float_as_uint(f);
    u += 0x7fffu + ((u >> 16) & 1u);
    return (ushort_t)(u >> 16);
}
__device__ __forceinline__ float bf2f(ushort_t u) {
    return __uint_as_float(((unsigned)u) << 16);
}
__device__ __forceinline__ float bf_lo(unsigned u) {
    return __uint_as_float(u << 16);
}
__device__ __forceinline__ float bf_hi(unsigned u) {
    return __uint_as_float(u & 0xffff0000u);
}

using frag_ab = __attribute__((ext_vector_type(8))) short;   // 8 bf16 = 4 VGPRs
using frag_cd = __attribute__((ext_vector_type(4))) float;   // 4 fp32

// ---------------- S1: bucket-staged binning (coalesced-chunk writes) --------
__global__ __launch_bounds__(256) void k_binstage(const int* __restrict__ row,
        const int* __restrict__ col, int* __restrict__ gcursor,
        unsigned* __restrict__ slab) {
    __shared__ int lcount[NBUCK];
    __shared__ int lbase[NBUCK];
    int t = threadIdx.x;
    for (int i = t; i < NBUCK; i += 256) lcount[i] = 0;
    __syncthreads();
    int base = blockIdx.x * EPB;
    unsigned rec[16]; int bp[16];
#pragma unroll
    for (int k = 0; k < 16; ++k) {
        int e = base + k * 256 + t;
        if (e < N_EDGES) {
            int r = row[e], c = col[e];
            int b = r >> 9;
            int pos = atomicAdd(&lcount[b], 1);          // LDS cursor
            rec[k] = ((unsigned)(r & 511) << 17) | (unsigned)c;  // 9+17 bits
            bp[k] = (b << 16) | pos;
        } else bp[k] = -1;
    }
    __syncthreads();
    for (int b = t; b < NBUCK; b += 256) {               // one chunk reservation/bucket
        int c = lcount[b];
        lbase[b] = (c > 0) ? atomicAdd(&gcursor[b], c) : 0;
    }
    __syncthreads();
#pragma unroll
    for (int k = 0; k < 16; ++k) {
        if (bp[k] >= 0) {
            int b = bp[k] >> 16, pos = bp[k] & 0xffff;
            slab[(size_t)b * BUCKCAP + lbase[b] + pos] = rec[k];
        }
    }
}

// ---------------- exclusive scan of 196 bucket totals -----------------------
__global__ void k_bucket_scan(const int* __restrict__ gcursor, int* __restrict__ gebase) {
    if (threadIdx.x == 0 && blockIdx.x == 0) {
        int run = 0;
        for (int b = 0; b < NBUCK; ++b) { gebase[b] = run; run += gcursor[b]; }
        gebase[NBUCK] = run;
    }
}

// ---------------- S2: per-bucket CSR build (window-local writes) ------------
__global__ __launch_bounds__(256) void k_bucket_build(const unsigned* __restrict__ slab,
        const int* __restrict__ gcursor, const int* __restrict__ gebase,
        int* __restrict__ start, int* __restrict__ counts, float* __restrict__ dinv,
        unsigned* __restrict__ csr4) {
    __shared__ int ncount[BUCKN];
    __shared__ int nstart[BUCKN];
    __shared__ int sc[256];
    int b = blockIdx.x, t = threadIdx.x;
    int cnt = gcursor[b];
    int ebase = gebase[b];
    int node0 = b * BUCKN;
    int nn = min(BUCKN, N_NODES - node0);
    for (int i = t; i < nn; i += 256) ncount[i] = 0;
    __syncthreads();
    const unsigned* sl = slab + (size_t)b * BUCKCAP;
    for (int i = t; i < cnt; i += 256)
        atomicAdd(&ncount[sl[i] >> 17], 1);
    __syncthreads();
    // exclusive scan of ncount[0..nn) with 256 threads x 2 elements
    int a0 = (2 * t < nn) ? ncount[2 * t] : 0;
    int a1 = (2 * t + 1 < nn) ? ncount[2 * t + 1] : 0;
    int ps = a0 + a1;
    sc[t] = ps; __syncthreads();
    for (int off = 1; off < 256; off <<= 1) {
        int v = (t >= off) ? sc[t - off] : 0;
        __syncthreads();
        sc[t] += v;
        __syncthreads();
    }
    int ex = sc[t] - ps;
    if (2 * t < nn) nstart[2 * t] = ex;
    if (2 * t + 1 < nn) nstart[2 * t + 1] = ex + a0;
    __syncthreads();
    for (int i = t; i < nn; i += 256) {
        int node = node0 + i;
        start[node] = ebase + nstart[i];
        int c = ncount[i];
        counts[node] = c;
        dinv[node] = rsqrtf((float)(c + 1));
    }
    __syncthreads();
    // scatter cols into the bucket's contiguous csr window; nstart reused as cursor
    for (int i = t; i < cnt; i += 256) {
        unsigned r = sl[i];
        int pos = atomicAdd(&nstart[r >> 17], 1);
        csr4[ebase + pos] = r & 0x1ffffu;
    }
}

// ---------------- h0 = x @ W_sgc + b_sgc via bf16 MFMA, bf16 output ---------
__global__ __launch_bounds__(256) void k_h0(const float* __restrict__ x,
        const float* __restrict__ W, const float* __restrict__ bias,
        ushort_t* __restrict__ h0b) {
    int wid = (blockIdx.x * 256 + (int)threadIdx.x) >> 6;
    int lane = threadIdx.x & 63;
    if (wid >= N_NODES / 16) return;
    int row0 = wid * 16;
    int m = lane & 15, q = lane >> 4;

    frag_ab bfr[2][4];
#pragma unroll
    for (int ks = 0; ks < 2; ++ks)
#pragma unroll
        for (int nt = 0; nt < 4; ++nt)
#pragma unroll
            for (int j = 0; j < 8; ++j)
                bfr[ks][nt][j] = (short)f2bf(W[(ks * 32 + q * 8 + j) * 64 + nt * 16 + m]);

    frag_ab afr[2];
#pragma unroll
    for (int ks = 0; ks < 2; ++ks) {
        const float4* xp = (const float4*)(x + (size_t)(row0 + m) * 64 + ks * 32 + q * 8);
        float4 v0 = xp[0], v1 = xp[1];
        afr[ks][0] = (short)f2bf(v0.x); afr[ks][1] = (short)f2bf(v0.y);
        afr[ks][2] = (short)f2bf(v0.z); afr[ks][3] = (short)f2bf(v0.w);
        afr[ks][4] = (short)f2bf(v1.x); afr[ks][5] = (short)f2bf(v1.y);
        afr[ks][6] = (short)f2bf(v1.z); afr[ks][7] = (short)f2bf(v1.w);
    }

    frag_cd acc[4];
#pragma unroll
    for (int nt = 0; nt < 4; ++nt) acc[nt] = (frag_cd){0.f, 0.f, 0.f, 0.f};
#pragma unroll
    for (int ks = 0; ks < 2; ++ks)
#pragma unroll
        for (int nt = 0; nt < 4; ++nt)
            acc[nt] = __builtin_amdgcn_mfma_f32_16x16x32_bf16(afr[ks], bfr[ks][nt], acc[nt], 0, 0, 0);

#pragma unroll
    for (int nt = 0; nt < 4; ++nt) {
        int cc = nt * 16 + m;
        float bl = bias[cc];
#pragma unroll
        for (int r = 0; r < 4; ++r) {
            int rr = row0 + q * 4 + r;
            h0b[(size_t)rr * 64 + cc] = f2bf(acc[nt][r] + bl);
        }
    }
}

// ---------------- propagation hop: 2 nodes/wave, bf16x2 per lane ------------
__device__ __forceinline__ void hop_acc2(int node, int l,
        const unsigned* __restrict__ hb_in, const unsigned* __restrict__ h0b,
        const float* __restrict__ dinv, const int* __restrict__ start,
        const int* __restrict__ counts, const unsigned* __restrict__ csr4,
        float& a0, float& a1) {
    float di = dinv[node];
    unsigned us = hb_in[node * 32 + l];
    unsigned u0 = h0b[node * 32 + l];
    float self = 0.5f * di * di;
    a0 = self * bf_lo(us) + 0.5f * bf_lo(u0);
    a1 = self * bf_hi(us) + 0.5f * bf_hi(u0);
    float C = 0.5f * di;
    int s = start[node], cnt = counts[node];
    int j = 0;
    for (; j + 4 <= cnt; j += 4) {
        unsigned c0 = csr4[s + j],     c1 = csr4[s + j + 1];
        unsigned c2 = csr4[s + j + 2], c3 = csr4[s + j + 3];
        float w0 = C * dinv[c0], w1 = C * dinv[c1];
        float w2 = C * dinv[c2], w3 = C * dinv[c3];
        unsigned v0 = hb_in[c0 * 32 + l];
        unsigned v1 = hb_in[c1 * 32 + l];
        unsigned v2 = hb_in[c2 * 32 + l];
        unsigned v3 = hb_in[c3 * 32 + l];
        a0 += w0 * bf_lo(v0); a1 += w0 * bf_hi(v0);
        a0 += w1 * bf_lo(v1); a1 += w1 * bf_hi(v1);
        a0 += w2 * bf_lo(v2); a1 += w2 * bf_hi(v2);
        a0 += w3 * bf_lo(v3); a1 += w3 * bf_hi(v3);
    }
    for (; j < cnt; ++j) {
        unsigned c0 = csr4[s + j];
        float w0 = C * dinv[c0];
        unsigned v0 = hb_in[c0 * 32 + l];
        a0 += w0 * bf_lo(v0); a1 += w0 * bf_hi(v0);
    }
}

__global__ void k_hop(const unsigned* __restrict__ hb_in, const unsigned* __restrict__ h0b,
                      const float* __restrict__ dinv, const int* __restrict__ start,
                      const int* __restrict__ counts, const unsigned* __restrict__ csr4,
                      unsigned* __restrict__ hb_out) {
    int node = blockIdx.x * 8 + ((int)threadIdx.x >> 5);
    int l = threadIdx.x & 31;
    float a0, a1;
    hop_acc2(node, l, hb_in, h0b, dinv, start, counts, csr4, a0, a1);
    hb_out[node * 32 + l] = ((unsigned)f2bf(a1) << 16) | (unsigned)f2bf(a0);
}

__global__ void k_hop_final(const unsigned* __restrict__ hb_in, const unsigned* __restrict__ h0b,
                            const float* __restrict__ dinv, const int* __restrict__ start,
                            const int* __restrict__ counts, const unsigned* __restrict__ csr4,
                            const float* __restrict__ w_att, const float* __restrict__ b_att,
                            unsigned* __restrict__ hb_out, float* __restrict__ v_raw) {
    int node = blockIdx.x * 8 + ((int)threadIdx.x >> 5);
    int l = threadIdx.x & 31;
    float a0, a1;
    hop_acc2(node, l, hb_in, h0b, dinv, start, counts, csr4, a0, a1);
    float h0v = fmaxf(a0, 0.f), h1v = fmaxf(a1, 0.f);
    hb_out[node * 32 + l] = ((unsigned)f2bf(h1v) << 16) | (unsigned)f2bf(h0v);
    float2 wa = *(const float2*)(w_att + 2 * l);
    float p = h0v * wa.x + h1v * wa.y;
#pragma unroll
    for (int off = 16; off >= 1; off >>= 1) p += __shfl_xor(p, off, 64);
    if (l == 0) {
        v_raw[node] = 1.f / (1.f + expf(-(p + b_att[0])));
    }
}

// ---------------- graph ranges via sorted-boundary detection ----------------
__global__ void k_bounds(const int* __restrict__ batch, int* __restrict__ gbound) {
    int n = blockIdx.x * blockDim.x + threadIdx.x;
    if (n >= N_NODES) return;
    int b = batch[n];
    int prev = (n == 0) ? -1 : batch[n - 1];
    for (int g = prev + 1; g <= b; ++g) gbound[g] = n;
    if (n == N_NODES - 1) {
        for (int g = b + 1; g <= NGRAPH; ++g) gbound[g] = N_NODES;
    }
}

// ---------------- readout + MLP head, one block per graph ----------------
__global__ void k_readout_mlp(const ushort_t* __restrict__ hb, const float* __restrict__ v_raw,
        const int* __restrict__ gbound,
        const float* __restrict__ W1, const float* __restrict__ b1,
        const float* __restrict__ W2, const float* __restrict__ b2,
        const float* __restrict__ W3, const float* __restrict__ b3,
        float* __restrict__ out) {
    int g = blockIdx.x, t = threadIdx.x;
    int s = gbound[g], e = gbound[g + 1];
    __shared__ float red[256];

    float m = -3.402823466e38f;
    for (int n = s + t; n < e; n += 256) m = fmaxf(m, v_raw[n]);
    red[t] = m; __syncthreads();
    for (int off = 128; off >= 1; off >>= 1) {
        if (t < off) red[t] = fmaxf(red[t], red[t + off]);
        __syncthreads();
    }
    float vmax = red[0]; __syncthreads();

    float ss = 0.f;
    for (int n = s + t; n < e; n += 256) ss += expf(v_raw[n] - vmax);
    red[t] = ss; __syncthreads();
    for (int off = 128; off >= 1; off >>= 1) {
        if (t < off) red[t] += red[t + off];
        __syncthreads();
    }
    float inv = 1.f / (red[0] + 1e-16f);
    __syncthreads();

    int wv = t >> 6, lane = t & 63;
    float gm = -3.402823466e38f, gs = 0.f;
    for (int n = s + wv; n < e; n += 4) {
        float hv = bf2f(hb[(size_t)n * 64 + lane]);
        float vn = expf(v_raw[n] - vmax) * inv;
        gm = fmaxf(gm, hv);
        gs += vn * hv;
    }
    __shared__ float pm[4][64], ps[4][64];
    pm[wv][lane] = gm; ps[wv][lane] = gs;
    __syncthreads();

    __shared__ float z[128];
    if (t < 64) {
        z[t] = fmaxf(fmaxf(pm[0][t], pm[1][t]), fmaxf(pm[2][t], pm[3][t]));
        z[64 + t] = ps[0][t] + ps[1][t] + ps[2][t] + ps[3][t];
    }
    __syncthreads();

    __shared__ float z1[64];
    if (t < 64) {
        float a = b1[t];
#pragma unroll 8
        for (int k = 0; k < 128; ++k) a += z[k] * W1[k * 64 + t];
        z1[t] = fmaxf(a, 0.f);
    }
    __syncthreads();
    __shared__ float z2[32];
    if (t < 32) {
        float a = b2[t];
#pragma unroll 8
        for (int k = 0; k < 64; ++k) a += z1[k] * W2[k * 32 + t];
        z2[t] = fmaxf(a, 0.f);
    }
    __syncthreads();
    __shared__ float z3[8];
    if (t < 8) {
        float a = b3[t];
#pragma unroll
        for (int k = 0; k < 32; ++k) a += z2[k] * W3[k * 8 + t];
        z3[t] = a;
    }
    __syncthreads();
    if (t == 0) {
        float mx = z3[0];
#pragma unroll
        for (int j = 1; j < 8; ++j) mx = fmaxf(mx, z3[j]);
        float se = 0.f;
#pragma unroll
        for (int j = 0; j < 8; ++j) se += expf(z3[j] - mx);
        float lse = mx + logf(se);
#pragma unroll
        for (int j = 0; j < 8; ++j) out[g * 8 + j] = z3[j] - lse;
    }
}

extern "C" void kernel_launch(void* const* d_in, const int* in_sizes, int n_in,
                              void* d_out, int out_size, void* d_ws, size_t ws_size,
                              hipStream_t stream) {
    const float* x     = (const float*)d_in[0];
    const int*   edge  = (const int*)d_in[1];
    const int*   row   = edge;
    const int*   col   = edge + N_EDGES;
    const int*   batch = (const int*)d_in[2];
    const float* W_sgc = (const float*)d_in[3];
    const float* b_sgc = (const float*)d_in[4];
    const float* w_att = (const float*)d_in[5];
    const float* b_att = (const float*)d_in[6];
    const float* W1    = (const float*)d_in[7];
    const float* b1    = (const float*)d_in[8];
    const float* W2    = (const float*)d_in[9];
    const float* b2    = (const float*)d_in[10];
    const float* W3    = (const float*)d_in[11];
    const float* b3    = (const float*)d_in[12];
    float* out = (float*)d_out;

    char* p = (char*)d_ws;
    auto alloc = [&](size_t bytes) {
        char* r = p;
        p += (bytes + 255) & ~(size_t)255;
        return r;
    };
    int*      gcursor = (int*)alloc((size_t)NBUCK * 4);
    int*      gebase  = (int*)alloc((size_t)(NBUCK + 1) * 4);
    int*      gbound  = (int*)alloc((size_t)(NGRAPH + 1) * 4);
    int*      start   = (int*)alloc((size_t)N_NODES * 4);
    int*      counts  = (int*)alloc((size_t)N_NODES * 4);
    float*    dinv    = (float*)alloc((size_t)N_NODES * 4);
    float*    vraw    = (float*)alloc((size_t)N_NODES * 4);
    ushort_t* h0b     = (ushort_t*)alloc((size_t)N_NODES * 64 * 2);
    ushort_t* hAb     = (ushort_t*)alloc((size_t)N_NODES * 64 * 2);
    ushort_t* hBb     = (ushort_t*)alloc((size_t)N_NODES * 64 * 2);
    unsigned* csr4    = (unsigned*)alloc((size_t)N_EDGES * 4);
    unsigned* slab    = (unsigned*)alloc((size_t)NBUCK * BUCKCAP * 4);

    // only the 196 bucket cursors need zeroing (everything else fully written)
    hipMemsetAsync(gcursor, 0, (size_t)NBUCK * 4, stream);

    k_binstage<<<(N_EDGES + EPB - 1) / EPB, 256, 0, stream>>>(row, col, gcursor, slab);
    k_bucket_scan<<<1, 64, 0, stream>>>(gcursor, gebase);
    k_bucket_build<<<NBUCK, 256, 0, stream>>>(slab, gcursor, gebase,
                                              start, counts, dinv, csr4);
    k_h0<<<(N_NODES / 16 + 3) / 4, 256, 0, stream>>>(x, W_sgc, b_sgc, h0b);
    k_hop<<<N_NODES / 8, 256, 0, stream>>>((const unsigned*)h0b, (const unsigned*)h0b,
                                           dinv, start, counts, csr4, (unsigned*)hAb);
    k_hop<<<N_NODES / 8, 256, 0, stream>>>((const unsigned*)hAb, (const unsigned*)h0b,
                                           dinv, start, counts, csr4, (unsigned*)hBb);
    k_hop_final<<<N_NODES / 8, 256, 0, stream>>>((const unsigned*)hBb, (const unsigned*)h0b,
                                                 dinv, start, counts, csr4,
                                                 w_att, b_att, (unsigned*)hAb, vraw);
    k_bounds<<<(N_NODES + 255) / 256, 256, 0, stream>>>(batch, gbound);
    k_readout_mlp<<<NGRAPH, 256, 0, stream>>>(hAb, vraw, gbound,
                                              W1, b1, W2, b2, W3, b3, out);
}

// Round 7
// 268.579 us; speedup vs baseline: 2.7397x; 1.0118x over previous
//
#include <hip/hip_runtime.h>
#include <math.h>

#define N_NODES 100000
#define N_EDGES 1000000
#define NGRAPH 256

#define NBUCK 196          // ceil(100000 / 512)
#define BUCKN 512
#define BUCKCAP 8192       // max raw edges/bucket (mean ~5120, ~40 sigma margin)
#define EPB 4096           // edges per S1 block
#define DUMMY ((unsigned)N_NODES)   // pad col -> node with hs == 0

typedef unsigned short ushort_t;

__device__ __forceinline__ ushort_t f2bf(float f) {   // round-to-nearest-even
    unsigned u = __float_as_uint(f);
    u += 0x7fffu + ((u >> 16) & 1u);
    return (ushort_t)(u >> 16);
}
__device__ __forceinline__ float bf2f(ushort_t u) {
    return __uint_as_float(((unsigned)u) << 16);
}
__device__ __forceinline__ float bf_lo(unsigned u) {
    return __uint_as_float(u << 16);
}
__device__ __forceinline__ float bf_hi(unsigned u) {
    return __uint_as_float(u & 0xffff0000u);
}
__device__ __forceinline__ unsigned pack2(float hi, float lo) {
    return ((unsigned)f2bf(hi) << 16) | (unsigned)f2bf(lo);
}

using frag_ab = __attribute__((ext_vector_type(8))) short;
using frag_cd = __attribute__((ext_vector_type(4))) float;

// ---------------- S1: bucket-staged binning (coalesced-chunk writes) --------
__global__ __launch_bounds__(256) void k_binstage(const int* __restrict__ row,
        const int* __restrict__ col, int* __restrict__ gcursor,
        unsigned* __restrict__ slab) {
    __shared__ int lcount[NBUCK];
    __shared__ int lbase[NBUCK];
    int t = threadIdx.x;
    for (int i = t; i < NBUCK; i += 256) lcount[i] = 0;
    __syncthreads();
    int base = blockIdx.x * EPB;
    unsigned rec[16]; int bp[16];
#pragma unroll
    for (int k = 0; k < 16; ++k) {
        int e = base + k * 256 + t;
        if (e < N_EDGES) {
            int r = row[e], c = col[e];
            int b = r >> 9;
            int pos = atomicAdd(&lcount[b], 1);
            rec[k] = ((unsigned)(r & 511) << 17) | (unsigned)c;
            bp[k] = (b << 16) | pos;
        } else bp[k] = -1;
    }
    __syncthreads();
    for (int b = t; b < NBUCK; b += 256) {
        int c = lcount[b];
        lbase[b] = (c > 0) ? atomicAdd(&gcursor[b], c) : 0;
    }
    __syncthreads();
#pragma unroll
    for (int k = 0; k < 16; ++k) {
        if (bp[k] >= 0) {
            int b = bp[k] >> 16, pos = bp[k] & 0xffff;
            slab[(size_t)b * BUCKCAP + lbase[b] + pos] = rec[k];
        }
    }
}

// ---------------- exclusive scan of bucket windows (padded-safe) ------------
__global__ void k_bucket_scan(const int* __restrict__ gcursor, int* __restrict__ gebase) {
    if (threadIdx.x == 0 && blockIdx.x == 0) {
        int run = 0;
        for (int b = 0; b < NBUCK; ++b) {
            gebase[b] = run;
            run += ((gcursor[b] + 3) & ~3) + 3 * BUCKN;  // room for per-node pad-to-4
        }
        gebase[NBUCK] = run;
    }
}

// ---------------- S2: per-bucket CSR build, segments padded to x4 -----------
__global__ __launch_bounds__(256) void k_bucket_build(const unsigned* __restrict__ slab,
        const int* __restrict__ gcursor, const int* __restrict__ gebase,
        int* __restrict__ start, int* __restrict__ counts, float* __restrict__ dinv,
        unsigned* __restrict__ csr4) {
    __shared__ int ncount[BUCKN];
    __shared__ int nstart[BUCKN];
    __shared__ int sc[256];
    int b = blockIdx.x, t = threadIdx.x;
    int cnt = gcursor[b];
    int ebase = gebase[b];
    int node0 = b * BUCKN;
    int nn = min(BUCKN, N_NODES - node0);
    for (int i = t; i < nn; i += 256) ncount[i] = 0;
    __syncthreads();
    const unsigned* sl = slab + (size_t)b * BUCKCAP;
    for (int i = t; i < cnt; i += 256)
        atomicAdd(&ncount[sl[i] >> 17], 1);
    __syncthreads();
    // exclusive scan of PADDED counts (multiples of 4)
    int c0 = (2 * t < nn) ? ncount[2 * t] : 0;
    int c1 = (2 * t + 1 < nn) ? ncount[2 * t + 1] : 0;
    int p0 = (c0 + 3) & ~3, p1 = (c1 + 3) & ~3;
    int ps = p0 + p1;
    sc[t] = ps; __syncthreads();
    for (int off = 1; off < 256; off <<= 1) {
        int v = (t >= off) ? sc[t - off] : 0;
        __syncthreads();
        sc[t] += v;
        __syncthreads();
    }
    int ex = sc[t] - ps;
    if (2 * t < nn) nstart[2 * t] = ex;
    if (2 * t + 1 < nn) nstart[2 * t + 1] = ex + p0;
    __syncthreads();
    // per-node metadata + fill pad slots with DUMMY
    for (int i = t; i < nn; i += 256) {
        int node = node0 + i;
        int c = ncount[i];
        int pc = (c + 3) & ~3;
        int st = ebase + nstart[i];
        start[node] = st;
        counts[node] = pc;                        // PADDED count for the hop
        dinv[node] = rsqrtf((float)(c + 1));      // true degree for normalization
        for (int k = c; k < pc; ++k) csr4[st + k] = DUMMY;
    }
    __syncthreads();
    // scatter cols; nstart reused as running cursor
    for (int i = t; i < cnt; i += 256) {
        unsigned r = sl[i];
        int pos = atomicAdd(&nstart[r >> 17], 1);
        csr4[ebase + pos] = r & 0x1ffffu;
    }
}

// ---------------- h0 = x @ W_sgc + b_sgc: plain bf16 + dinv-scaled bf16 -----
__global__ __launch_bounds__(256) void k_h0(const float* __restrict__ x,
        const float* __restrict__ W, const float* __restrict__ bias,
        const float* __restrict__ dinv,
        ushort_t* __restrict__ h0b, ushort_t* __restrict__ h0s) {
    int wid = (blockIdx.x * 256 + (int)threadIdx.x) >> 6;
    int lane = threadIdx.x & 63;
    if (wid >= N_NODES / 16) return;
    int row0 = wid * 16;
    int m = lane & 15, q = lane >> 4;

    frag_ab bfr[2][4];
#pragma unroll
    for (int ks = 0; ks < 2; ++ks)
#pragma unroll
        for (int nt = 0; nt < 4; ++nt)
#pragma unroll
            for (int j = 0; j < 8; ++j)
                bfr[ks][nt][j] = (short)f2bf(W[(ks * 32 + q * 8 + j) * 64 + nt * 16 + m]);

    frag_ab afr[2];
#pragma unroll
    for (int ks = 0; ks < 2; ++ks) {
        const float4* xp = (const float4*)(x + (size_t)(row0 + m) * 64 + ks * 32 + q * 8);
        float4 v0 = xp[0], v1 = xp[1];
        afr[ks][0] = (short)f2bf(v0.x); afr[ks][1] = (short)f2bf(v0.y);
        afr[ks][2] = (short)f2bf(v0.z); afr[ks][3] = (short)f2bf(v0.w);
        afr[ks][4] = (short)f2bf(v1.x); afr[ks][5] = (short)f2bf(v1.y);
        afr[ks][6] = (short)f2bf(v1.z); afr[ks][7] = (short)f2bf(v1.w);
    }

    frag_cd acc[4];
#pragma unroll
    for (int nt = 0; nt < 4; ++nt) acc[nt] = (frag_cd){0.f, 0.f, 0.f, 0.f};
#pragma unroll
    for (int ks = 0; ks < 2; ++ks)
#pragma unroll
        for (int nt = 0; nt < 4; ++nt)
            acc[nt] = __builtin_amdgcn_mfma_f32_16x16x32_bf16(afr[ks], bfr[ks][nt], acc[nt], 0, 0, 0);

    float dv[4];
#pragma unroll
    for (int r = 0; r < 4; ++r) dv[r] = dinv[row0 + q * 4 + r];

#pragma unroll
    for (int nt = 0; nt < 4; ++nt) {
        int cc = nt * 16 + m;
        float bl = bias[cc];
#pragma unroll
        for (int r = 0; r < 4; ++r) {
            int rr = row0 + q * 4 + r;
            float hv = acc[nt][r] + bl;
            h0b[(size_t)rr * 64 + cc] = f2bf(hv);
            h0s[(size_t)rr * 64 + cc] = f2bf(hv * dv[r]);
        }
    }
    if (wid == 0) h0s[(size_t)N_NODES * 64 + lane] = 0;   // dummy row = 0
}

// ---------------- hop inner sum: pure gather of pre-scaled hs ---------------
__device__ __forceinline__ void hop_sum(int node, int l,
        const unsigned* __restrict__ hs_in, const int* __restrict__ start,
        const int* __restrict__ counts, const unsigned* __restrict__ csr4,
        float& a0, float& a1) {
    unsigned us = hs_in[node * 32 + l];
    a0 = bf_lo(us); a1 = bf_hi(us);           // self-loop term (hs form)
    int s = start[node], cnt = counts[node];  // cnt % 4 == 0, s 16B-aligned
    for (int j = 0; j < cnt; j += 4) {
        uint4 cc = *(const uint4*)(csr4 + s + j);   // broadcast, addr-independent
        unsigned v0 = hs_in[cc.x * 32 + l];
        unsigned v1 = hs_in[cc.y * 32 + l];
        unsigned v2 = hs_in[cc.z * 32 + l];
        unsigned v3 = hs_in[cc.w * 32 + l];
        a0 += bf_lo(v0); a1 += bf_hi(v0);
        a0 += bf_lo(v1); a1 += bf_hi(v1);
        a0 += bf_lo(v2); a1 += bf_hi(v2);
        a0 += bf_lo(v3); a1 += bf_hi(v3);
    }
}

// intermediate hop: writes hs_out = dinv * h_new (bf16)
__global__ void k_hop(const unsigned* __restrict__ hs_in, const unsigned* __restrict__ h0b,
                      const float* __restrict__ dinv, const int* __restrict__ start,
                      const int* __restrict__ counts, const unsigned* __restrict__ csr4,
                      unsigned* __restrict__ hs_out) {
    int node = blockIdx.x * 8 + ((int)threadIdx.x >> 5);
    int l = threadIdx.x & 31;
    float a0, a1;
    hop_sum(node, l, hs_in, start, counts, csr4, a0, a1);
    float di = dinv[node];
    unsigned u0 = h0b[node * 32 + l];
    float hn0 = 0.5f * di * a0 + 0.5f * bf_lo(u0);
    float hn1 = 0.5f * di * a1 + 0.5f * bf_hi(u0);
    hs_out[node * 32 + l] = pack2(hn1 * di, hn0 * di);
    if (blockIdx.x == 0 && threadIdx.x < 32)
        hs_out[N_NODES * 32 + threadIdx.x] = 0;           // dummy row = 0
}

// final hop: plain h out (relu) + attention gate
__global__ void k_hop_final(const unsigned* __restrict__ hs_in, const unsigned* __restrict__ h0b,
                            const float* __restrict__ dinv, const int* __restrict__ start,
                            const int* __restrict__ counts, const unsigned* __restrict__ csr4,
                            const float* __restrict__ w_att, const float* __restrict__ b_att,
                            unsigned* __restrict__ h_out, float* __restrict__ v_raw) {
    int node = blockIdx.x * 8 + ((int)threadIdx.x >> 5);
    int l = threadIdx.x & 31;
    float a0, a1;
    hop_sum(node, l, hs_in, start, counts, csr4, a0, a1);
    float di = dinv[node];
    unsigned u0 = h0b[node * 32 + l];
    float h0v = fmaxf(0.5f * di * a0 + 0.5f * bf_lo(u0), 0.f);
    float h1v = fmaxf(0.5f * di * a1 + 0.5f * bf_hi(u0), 0.f);
    h_out[node * 32 + l] = pack2(h1v, h0v);
    float2 wa = *(const float2*)(w_att + 2 * l);
    float p = h0v * wa.x + h1v * wa.y;
#pragma unroll
    for (int off = 16; off >= 1; off >>= 1) p += __shfl_xor(p, off, 64);
    if (l == 0) {
        v_raw[node] = 1.f / (1.f + expf(-(p + b_att[0])));
    }
}

// ---------------- graph ranges via sorted-boundary detection ----------------
__global__ void k_bounds(const int* __restrict__ batch, int* __restrict__ gbound) {
    int n = blockIdx.x * blockDim.x + threadIdx.x;
    if (n >= N_NODES) return;
    int b = batch[n];
    int prev = (n == 0) ? -1 : batch[n - 1];
    for (int g = prev + 1; g <= b; ++g) gbound[g] = n;
    if (n == N_NODES - 1) {
        for (int g = b + 1; g <= NGRAPH; ++g) gbound[g] = N_NODES;
    }
}

// ---------------- readout + MLP head, one block per graph ----------------
__global__ void k_readout_mlp(const ushort_t* __restrict__ hb, const float* __restrict__ v_raw,
        const int* __restrict__ gbound,
        const float* __restrict__ W1, const float* __restrict__ b1,
        const float* __restrict__ W2, const float* __restrict__ b2,
        const float* __restrict__ W3, const float* __restrict__ b3,
        float* __restrict__ out) {
    int g = blockIdx.x, t = threadIdx.x;
    int s = gbound[g], e = gbound[g + 1];
    __shared__ float red[256];

    float m = -3.402823466e38f;
    for (int n = s + t; n < e; n += 256) m = fmaxf(m, v_raw[n]);
    red[t] = m; __syncthreads();
    for (int off = 128; off >= 1; off >>= 1) {
        if (t < off) red[t] = fmaxf(red[t], red[t + off]);
        __syncthreads();
    }
    float vmax = red[0]; __syncthreads();

    float ss = 0.f;
    for (int n = s + t; n < e; n += 256) ss += expf(v_raw[n] - vmax);
    red[t] = ss; __syncthreads();
    for (int off = 128; off >= 1; off >>= 1) {
        if (t < off) red[t] += red[t + off];
        __syncthreads();
    }
    float inv = 1.f / (red[0] + 1e-16f);
    __syncthreads();

    int wv = t >> 6, lane = t & 63;
    float gm = -3.402823466e38f, gs = 0.f;
    for (int n = s + wv; n < e; n += 4) {
        float hv = bf2f(hb[(size_t)n * 64 + lane]);
        float vn = expf(v_raw[n] - vmax) * inv;
        gm = fmaxf(gm, hv);
        gs += vn * hv;
    }
    __shared__ float pm[4][64], ps[4][64];
    pm[wv][lane] = gm; ps[wv][lane] = gs;
    __syncthreads();

    __shared__ float z[128];
    if (t < 64) {
        z[t] = fmaxf(fmaxf(pm[0][t], pm[1][t]), fmaxf(pm[2][t], pm[3][t]));
        z[64 + t] = ps[0][t] + ps[1][t] + ps[2][t] + ps[3][t];
    }
    __syncthreads();

    __shared__ float z1[64];
    if (t < 64) {
        float a = b1[t];
#pragma unroll 8
        for (int k = 0; k < 128; ++k) a += z[k] * W1[k * 64 + t];
        z1[t] = fmaxf(a, 0.f);
    }
    __syncthreads();
    __shared__ float z2[32];
    if (t < 32) {
        float a = b2[t];
#pragma unroll 8
        for (int k = 0; k < 64; ++k) a += z1[k] * W2[k * 32 + t];
        z2[t] = fmaxf(a, 0.f);
    }
    __syncthreads();
    __shared__ float z3[8];
    if (t < 8) {
        float a = b3[t];
#pragma unroll
        for (int k = 0; k < 32; ++k) a += z2[k] * W3[k * 8 + t];
        z3[t] = a;
    }
    __syncthreads();
    if (t == 0) {
        float mx = z3[0];
#pragma unroll
        for (int j = 1; j < 8; ++j) mx = fmaxf(mx, z3[j]);
        float se = 0.f;
#pragma unroll
        for (int j = 0; j < 8; ++j) se += expf(z3[j] - mx);
        float lse = mx + logf(se);
#pragma unroll
        for (int j = 0; j < 8; ++j) out[g * 8 + j] = z3[j] - lse;
    }
}

extern "C" void kernel_launch(void* const* d_in, const int* in_sizes, int n_in,
                              void* d_out, int out_size, void* d_ws, size_t ws_size,
                              hipStream_t stream) {
    const float* x     = (const float*)d_in[0];
    const int*   edge  = (const int*)d_in[1];
    const int*   row   = edge;
    const int*   col   = edge + N_EDGES;
    const int*   batch = (const int*)d_in[2];
    const float* W_sgc = (const float*)d_in[3];
    const float* b_sgc = (const float*)d_in[4];
    const float* w_att = (const float*)d_in[5];
    const float* b_att = (const float*)d_in[6];
    const float* W1    = (const float*)d_in[7];
    const float* b1    = (const float*)d_in[8];
    const float* W2    = (const float*)d_in[9];
    const float* b2    = (const float*)d_in[10];
    const float* W3    = (const float*)d_in[11];
    const float* b3    = (const float*)d_in[12];
    float* out = (float*)d_out;

    char* p = (char*)d_ws;
    auto alloc = [&](size_t bytes) {
        char* r = p;
        p += (bytes + 255) & ~(size_t)255;
        return r;
    };
    int*      gcursor = (int*)alloc((size_t)NBUCK * 4);
    int*      gebase  = (int*)alloc((size_t)(NBUCK + 1) * 4);
    int*      gbound  = (int*)alloc((size_t)(NGRAPH + 1) * 4);
    int*      start   = (int*)alloc((size_t)N_NODES * 4);
    int*      counts  = (int*)alloc((size_t)N_NODES * 4);
    float*    dinv    = (float*)alloc((size_t)N_NODES * 4);
    float*    vraw    = (float*)alloc((size_t)N_NODES * 4);
    ushort_t* h0b     = (ushort_t*)alloc((size_t)N_NODES * 64 * 2);
    ushort_t* h0s     = (ushort_t*)alloc((size_t)(N_NODES + 1) * 64 * 2);
    ushort_t* hAs     = (ushort_t*)alloc((size_t)(N_NODES + 1) * 64 * 2);
    ushort_t* hBs     = (ushort_t*)alloc((size_t)(N_NODES + 1) * 64 * 2);
    unsigned* csr4    = (unsigned*)alloc(((size_t)N_EDGES + (size_t)NBUCK * 3 * BUCKN + 64) * 4);
    unsigned* slab    = (unsigned*)alloc((size_t)NBUCK * BUCKCAP * 4);

    hipMemsetAsync(gcursor, 0, (size_t)NBUCK * 4, stream);

    k_binstage<<<(N_EDGES + EPB - 1) / EPB, 256, 0, stream>>>(row, col, gcursor, slab);
    k_bucket_scan<<<1, 64, 0, stream>>>(gcursor, gebase);
    k_bucket_build<<<NBUCK, 256, 0, stream>>>(slab, gcursor, gebase,
                                              start, counts, dinv, csr4);
    k_h0<<<(N_NODES / 16 + 3) / 4, 256, 0, stream>>>(x, W_sgc, b_sgc, dinv, h0b, h0s);
    k_hop<<<N_NODES / 8, 256, 0, stream>>>((const unsigned*)h0s, (const unsigned*)h0b,
                                           dinv, start, counts, csr4, (unsigned*)hAs);
    k_hop<<<N_NODES / 8, 256, 0, stream>>>((const unsigned*)hAs, (const unsigned*)h0b,
                                           dinv, start, counts, csr4, (unsigned*)hBs);
    k_hop_final<<<N_NODES / 8, 256, 0, stream>>>((const unsigned*)hBs, (const unsigned*)h0b,
                                                 dinv, start, counts, csr4,
                                                 w_att, b_att, (unsigned*)hAs, vraw);
    k_bounds<<<(N_NODES + 255) / 256, 256, 0, stream>>>(batch, gbound);
    k_readout_mlp<<<NGRAPH, 256, 0, stream>>>(hAs, vraw, gbound,
                                              W1, b1, W2, b2, W3, b3, out);
}